// Round 13
// baseline (2702.485 us; speedup 1.0000x reference)
//
#include <hip/hip_runtime.h>
#include <math.h>

#define L_IN 65494
#define T_POOL 21490
#define TPP 21496          // fp16 h row stride (16B-aligned rows)
#define KF 1025
#define RS 1144            // conv replica row stride (elements)
#define NCH 141            // 8-col chunks per replica row
#define KEMB 21490
#define KEMBP 21504        // padded
#define NKC 1344           // KEMBP/16
#define FTILE 33280        // 65*512 shorts per conv filter tile
#define LWSZ 786432        // packed layer-weight shorts per layer

typedef short s16x4 __attribute__((ext_vector_type(4)));
typedef _Float16 f16x8 __attribute__((ext_vector_type(8)));
typedef float f32x4 __attribute__((ext_vector_type(4)));
typedef float f32x16 __attribute__((ext_vector_type(16)));

__device__ inline float selu_f(float x) {
    float e = expf(fminf(x, 0.f));
    float neg = 1.6732632423543772f * (e - 1.f);
    return 1.0507009873554805f * (x > 0.f ? x : neg);
}

__device__ inline float gelu_f(float x) {
    return 0.5f * x * (1.f + erff(x * 0.7071067811865476f));
}

__device__ inline float dot4(float4 a, float4 b) {
    return fmaf(a.x, b.x, fmaf(a.y, b.y, fmaf(a.z, b.z, a.w * b.w)));
}

__device__ inline float sel4(float a0, float a1, float a2, float a3, int i) {
    float r = a0;
    r = (i == 1) ? a1 : r;
    r = (i == 2) ? a2 : r;
    r = (i == 3) ? a3 : r;
    return r;
}

__device__ inline short f2h_bits(float v) {
    _Float16 h = (_Float16)v;
    return *(short*)&h;
}

// x = hi + lo in fp16 (hi RTNE, lo = residual): exact to ~2^-22
__device__ inline void f16split(float v, short& hs, short& ls) {
    _Float16 h = (_Float16)v;
    float hf = (float)h;
    _Float16 l = (_Float16)(v - hf);
    hs = *(short*)&h;
    ls = *(short*)&l;
}

__device__ inline void f16split2(float v, _Float16& h, _Float16& l) {
    h = (_Float16)v;
    l = (_Float16)(v - (float)h);
}

// ---------------- filter pack: fp16 single, fragment-major [ft][kc][lane][8] ----------------
__global__ __launch_bounds__(512)
void filt_pack_kernel(const float* __restrict__ filt, short* __restrict__ fpH) {
    int blk = blockIdx.x;            // ft*65 + kc  (grid 520)
    int ft = blk / 65, kc = blk % 65;
    int t = threadIdx.x, lane = t >> 3, e = t & 7;
    int f = ft * 32 + (lane & 31);
    int tap = kc * 16 + (lane >> 5) * 8 + e;
    float v = (tap < KF) ? filt[f * KF + tap] : 0.f;
    fpH[blk * 512 + t] = f2h_bits(v);
}

// ---------------- emb_w pack: fp16 single, fragment-major [ft][kc][lane][8] ----------------
__global__ __launch_bounds__(512)
void wpack_kernel(const float* __restrict__ wsrc, short* __restrict__ wpH) {
    int blk = blockIdx.x;            // ft*NKC + kc  (grid 8*NKC)
    int ft = blk / NKC, kc = blk % NKC;
    int t = threadIdx.x, lane = t >> 3, e = t & 7;
    int row = ft * 32 + (lane & 31);
    int tap = kc * 16 + (lane >> 5) * 8 + e;
    float v = (tap < KEMB) ? wsrc[(long)row * KEMB + tap] : 0.f;
    wpH[(long)blk * 512 + t] = f2h_bits(v);
}

// ---------------- layer weight pack: fp16 fragment-major for 16x16x32 B-operand ----------------
__global__ __launch_bounds__(512)
void lwpack_kernel(const float* __restrict__ wo, const float* __restrict__ wq,
                   const float* __restrict__ wk, const float* __restrict__ wv,
                   const float* __restrict__ c1w, const float* __restrict__ c2w,
                   short* __restrict__ lw) {
    int b = blockIdx.x;              // grid 4*1536
    int layer = b / 1536, r = b % 1536;
    int t = threadIdx.x, lane = t >> 3, e = t & 7;
    const float* src;
    int K, t2;
    long dst;
    if (r < 512) {
        int mat = r >> 7; t2 = r & 127;
        const float* m0 = (mat == 0 ? wo : mat == 1 ? wq : mat == 2 ? wk : wv);
        src = m0 + (long)layer * 65536; K = 256;
        dst = (long)layer * LWSZ + (long)mat * 65536 + (long)t2 * 512;
    } else if (r < 1024) {
        t2 = r - 512;
        src = c1w + (long)layer * 262144; K = 256;
        dst = (long)layer * LWSZ + 262144 + (long)t2 * 512;
    } else {
        t2 = r - 1024;
        src = c2w + (long)layer * 262144; K = 1024;
        dst = (long)layer * LWSZ + 524288 + (long)t2 * 512;
    }
    int KB = K >> 5;
    int nt = t2 / KB, kb = t2 % KB;
    int n = nt * 16 + (lane & 15);
    int k = kb * 32 + ((lane >> 4) & 3) * 8 + e;
    lw[dst + t] = f2h_bits(src[(long)n * K + k]);
}

// ---------------- MFMA projection helper: one 16-col tile, M=16-padded (4 real rows) ----------
__device__ inline f32x4 mfma_nt(const _Float16* __restrict__ Xh, const _Float16* __restrict__ Xl,
                                int xstride, const short* __restrict__ wp_nt, int KB, int lane) {
    f32x4 acc = {0.f, 0.f, 0.f, 0.f};
    const int row = (lane & 15) & 3;
    const int ko0 = ((lane >> 4) & 3) * 8;
    const short* bp = wp_nt + lane * 8;
    const _Float16* xh = Xh + row * xstride + ko0;
    const _Float16* xl = Xl + row * xstride + ko0;
#pragma unroll 4
    for (int kb = 0; kb < KB; kb++) {
        f16x8 bf = *(const f16x8*)(bp + kb * 512);
        f16x8 ah = *(const f16x8*)(xh + kb * 32);
        f16x8 al = *(const f16x8*)(xl + kb * 32);
        acc = __builtin_amdgcn_mfma_f32_16x16x32_f16(al, bf, acc, 0, 0, 0);
        acc = __builtin_amdgcn_mfma_f32_16x16x32_f16(ah, bf, acc, 0, 0, 0);
    }
    return acc;
}

// ---------------- SincConv via MFMA (fp16 single-pass) + |.| + maxpool3 ----------------
// Slim-LDS variant: 8-pass epilogue with ebuf[96][33] -> LDS ~18.4 KB, high occupancy.
union ConvLDS {
    short xh[8][RS];
    float ebuf[96][33];
};

#define MFMA2(ACC, AH, AL, BH) \
    ACC = __builtin_amdgcn_mfma_f32_32x32x16_f16(AL, BH, ACC, 0, 0, 0); \
    ACC = __builtin_amdgcn_mfma_f32_32x32x16_f16(AH, BH, ACC, 0, 0, 0);

__global__ __launch_bounds__(256, 6)
void conv_mfma_kernel(const float* __restrict__ x, const short* __restrict__ fpH,
                      _Float16* __restrict__ h) {
    __shared__ ConvLDS u;
    const int tid = threadIdx.x;
    const int pb = blockIdx.x;
    const int b = blockIdx.y;
    const int t0 = pb * 96;
    const float* xb = x + (long)b * L_IN;

    // staging: thread owns (replica s, 8-col chunk j); single fp16, b128 writes.
    if (pb < 671) {
        for (int idx = tid; idx < 8 * NCH; idx += 256) {
            int s = idx / NCH, j = idx - s * NCH;
            int gi = t0 + s + j * 8;
            f16x8 hv;
#pragma unroll
            for (int e = 0; e < 8; e++) hv[e] = (_Float16)xb[gi + e];
            *(f16x8*)&u.xh[s][j * 8] = hv;
        }
    } else {
        for (int idx = tid; idx < 8 * NCH; idx += 256) {
            int s = idx / NCH, j = idx - s * NCH;
            int gi = t0 + s + j * 8;
            f16x8 hv;
#pragma unroll
            for (int e = 0; e < 8; e++) {
                float v = (gi + e < L_IN) ? xb[gi + e] : 0.f;
                hv[e] = (_Float16)v;
            }
            *(f16x8*)&u.xh[s][j * 8] = hv;
        }
    }
    __syncthreads();

    const int lane = tid & 63;
    const int wid = tid >> 6;
    const int l31 = lane & 31;
    const int hi = lane >> 5;

    const short* aH = &u.xh[l31 & 7][8 * (l31 >> 3) + 8 * hi];
    const short* bp0 = fpH + (long)(wid * 2) * FTILE + lane * 8;
    const short* bp1 = bp0 + FTILE;

    f32x16 a00 = {0}, a01 = {0}, a10 = {0}, a11 = {0}, a20 = {0}, a21 = {0};

#pragma unroll 1
    for (int kc = 0; kc < 65; kc++) {
        const int ko = kc * 16;
        const int kf = kc * 512;
        f16x8 ah0 = *(const f16x8*)(aH + ko);
        f16x8 ah1 = *(const f16x8*)(aH + ko + 32);
        f16x8 ah2 = *(const f16x8*)(aH + ko + 64);
        f16x8 bh0 = *(const f16x8*)(bp0 + kf);
        f16x8 bh1 = *(const f16x8*)(bp1 + kf);
        a00 = __builtin_amdgcn_mfma_f32_32x32x16_f16(ah0, bh0, a00, 0, 0, 0);
        a01 = __builtin_amdgcn_mfma_f32_32x32x16_f16(ah0, bh1, a01, 0, 0, 0);
        a10 = __builtin_amdgcn_mfma_f32_32x32x16_f16(ah1, bh0, a10, 0, 0, 0);
        a11 = __builtin_amdgcn_mfma_f32_32x32x16_f16(ah1, bh1, a11, 0, 0, 0);
        a20 = __builtin_amdgcn_mfma_f32_32x32x16_f16(ah2, bh0, a20, 0, 0, 0);
        a21 = __builtin_amdgcn_mfma_f32_32x32x16_f16(ah2, bh1, a21, 0, 0, 0);
    }

    __syncthreads();
    const int t3l = tid & 31;
    const int t3 = pb * 32 + t3l;
    const int c0 = tid >> 5;       // 0..7

#define WRF1(ACC, MT)                                                      \
    {                                                                      \
        _Pragma("unroll")                                                  \
        for (int r = 0; r < 16; r++) {                                     \
            int pos = MT * 32 + (r & 3) + 8 * (r >> 2) + 4 * hi;           \
            u.ebuf[pos][l31] = fabsf(ACC[r]);                              \
        }                                                                  \
    }
#pragma unroll 1
    for (int fb = 0; fb < 8; fb++) {
        if (wid == (fb >> 1)) {
            if ((fb & 1) == 0) { WRF1(a00, 0) WRF1(a10, 1) WRF1(a20, 2) }
            else               { WRF1(a01, 0) WRF1(a11, 1) WRF1(a21, 2) }
        }
        __syncthreads();
        if (t3 < T_POOL) {
#pragma unroll
            for (int cc = c0; cc < 32; cc += 8) {
                float v = fmaxf(fmaxf(u.ebuf[3 * t3l][cc], u.ebuf[3 * t3l + 1][cc]),
                                u.ebuf[3 * t3l + 2][cc]);
                h[((long)(b * 256 + fb * 32 + cc)) * TPP + t3] = (_Float16)v;
            }
        }
        __syncthreads();
    }
#undef WRF1
}

// ---------------- BatchNorm stats for h (fp16): two-stage ----------------
__global__ __launch_bounds__(256)
void bn_part_kernel(const _Float16* __restrict__ xin, float* __restrict__ p1,
                    float* __restrict__ p2) {
    __shared__ float sm[8];
    int c = blockIdx.x, s = blockIdx.y, tid = threadIdx.x;
    int t0 = s * 2687, t1 = min(T_POOL, t0 + 2687);
    float s1 = 0.f, s2 = 0.f;
    for (int b = 0; b < 4; b++) {
        const _Float16* p = xin + (long)b * 256 * TPP + (long)c * TPP;
        for (int t = t0 + tid; t < t1; t += 256) {
            float v = (float)p[t];
            s1 += v;
            s2 = fmaf(v, v, s2);
        }
    }
    for (int off = 32; off > 0; off >>= 1) { s1 += __shfl_down(s1, off); s2 += __shfl_down(s2, off); }
    int lane = tid & 63, wv = tid >> 6;
    if (lane == 0) { sm[wv] = s1; sm[4 + wv] = s2; }
    __syncthreads();
    if (tid == 0) {
        p1[c * 8 + s] = sm[0] + sm[1] + sm[2] + sm[3];
        p2[c * 8 + s] = sm[4] + sm[5] + sm[6] + sm[7];
    }
}

__global__ __launch_bounds__(256)
void bn_fin_kernel(const float* __restrict__ p1, const float* __restrict__ p2,
                   const float* __restrict__ g, const float* __restrict__ bb,
                   float* __restrict__ sc, float* __restrict__ sh) {
    int c = threadIdx.x;
    float S1 = 0.f, S2 = 0.f;
#pragma unroll
    for (int s = 0; s < 8; s++) { S1 += p1[c * 8 + s]; S2 += p2[c * 8 + s]; }
    float n = 4.f * (float)T_POOL;
    float mean = S1 / n;
    float var = S2 / n - mean * mean;
    float rstd = rsqrtf(var + 1e-5f);
    float gc = g[c], bc = bb[c];
    sc[c] = rstd * gc;
    sh[c] = bc - mean * rstd * gc;
}

// ---------------- BatchNorm stats (small, for e) ----------------
__global__ __launch_bounds__(256)
void bn_stats_kernel(const float* __restrict__ xin, const float* __restrict__ g,
                     const float* __restrict__ bb, float* __restrict__ sc,
                     float* __restrict__ sh, int ilen, long bstride) {
    __shared__ float sm[8];
    int c = blockIdx.x, tid = threadIdx.x;
    float s1 = 0.f, s2 = 0.f;
    for (int b = 0; b < 4; b++) {
        const float* p = xin + b * bstride + (long)c * ilen;
        for (int t = tid; t < ilen; t += 256) {
            float v = p[t];
            s1 += v;
            s2 = fmaf(v, v, s2);
        }
    }
    for (int off = 32; off > 0; off >>= 1) { s1 += __shfl_down(s1, off); s2 += __shfl_down(s2, off); }
    int lane = tid & 63, wv = tid >> 6;
    if (lane == 0) { sm[wv] = s1; sm[4 + wv] = s2; }
    __syncthreads();
    if (tid == 0) {
        float S1 = sm[0] + sm[1] + sm[2] + sm[3];
        float S2 = sm[4] + sm[5] + sm[6] + sm[7];
        float n = 4.f * (float)ilen;
        float mean = S1 / n;
        float var = S2 / n - mean * mean;
        float rstd = rsqrtf(var + 1e-5f);
        float gc = g[c], bc = bb[c];
        sc[c] = rstd * gc;
        sh[c] = bc - mean * rstd * gc;
    }
}

// ---------------- Embedding GEMM via MFMA (fp16 2-pass), split-K, packed B ----------------
__global__ __launch_bounds__(256, 2)
void embed_mfma_kernel(const _Float16* __restrict__ H, const short* __restrict__ Wh,
                       const float* __restrict__ sc, const float* __restrict__ sh,
                       float* __restrict__ P, int kPerZ) {
    __shared__ short Ah[128][36];
    __shared__ short Al[128][36];
    const int tid = threadIdx.x;
    const int rowBase = blockIdx.x * 128;
    const int colBase = blockIdx.y * 128;
    const int z = blockIdx.z;
    const int kz = z * kPerZ;
    const int iters = kPerZ >> 5;

    const int trow = tid >> 1, th = (tid & 1) * 16;
    const int arow = rowBase + trow;
    const float asc = sc[arow & 255], ash_ = sh[arow & 255];
    const _Float16* Ap = H + (long)arow * TPP;

    const int lane = tid & 63, wid = tid >> 6;
    const int l31 = lane & 31, hi = lane >> 5;
    const int wm = wid >> 1, wn = wid & 1;

    const short* bhp[2];
#pragma unroll
    for (int nt = 0; nt < 2; nt++) {
        int ft = (colBase >> 5) + wn * 2 + nt;
        bhp[nt] = Wh + (long)ft * NKC * 512 + lane * 8;
    }

    f32x16 acc[2][2] = {{{0}, {0}}, {{0}, {0}}};

    for (int it = 0; it < iters; it++) {
        const int k0 = kz + it * 32;
        __syncthreads();
        float av[16];
        if (k0 + 32 <= KEMB) {
            const f16x8* p8 = (const f16x8*)(Ap + k0 + th);
            f16x8 v0 = p8[0], v1 = p8[1];
#pragma unroll
            for (int e = 0; e < 8; e++) { av[e] = (float)v0[e]; av[8 + e] = (float)v1[e]; }
        } else {
#pragma unroll
            for (int e = 0; e < 16; e++) {
                int k = k0 + th + e;
                av[e] = (k < KEMB) ? (float)Ap[k] : 0.f;
            }
        }
#pragma unroll
        for (int q = 0; q < 4; q++) {
            s16x4 h4, l4;
#pragma unroll
            for (int e = 0; e < 4; e++) {
                float v = selu_f(fmaf(av[q * 4 + e], asc, ash_));
                short hs, ls;
                f16split(v, hs, ls);
                h4[e] = hs; l4[e] = ls;
            }
            *(s16x4*)&Ah[trow][th + q * 4] = h4;
            *(s16x4*)&Al[trow][th + q * 4] = l4;
        }
        __syncthreads();

#pragma unroll
        for (int ks = 0; ks < 2; ks++) {
            const int kloc = ks * 16 + hi * 8;
            const long kcg = (long)((k0 >> 4) + ks) * 512;
            f16x8 ah[2], al[2], bh[2];
#pragma unroll
            for (int mt = 0; mt < 2; mt++) {
                const int r = wm * 64 + mt * 32 + l31;
                const short* ph = &Ah[r][kloc];
                const short* pl = &Al[r][kloc];
                union { f16x8 v; unsigned long long q[2]; } uh, ul;
                uh.q[0] = *(const unsigned long long*)(ph);
                uh.q[1] = *(const unsigned long long*)(ph + 4);
                ul.q[0] = *(const unsigned long long*)(pl);
                ul.q[1] = *(const unsigned long long*)(pl + 4);
                ah[mt] = uh.v; al[mt] = ul.v;
            }
#pragma unroll
            for (int nt = 0; nt < 2; nt++)
                bh[nt] = *(const f16x8*)(bhp[nt] + kcg);
#pragma unroll
            for (int mt = 0; mt < 2; mt++)
#pragma unroll
                for (int nt = 0; nt < 2; nt++) {
                    MFMA2(acc[mt][nt], ah[mt], al[mt], bh[nt])
                }
        }
    }

    float* Pz = P + (long)z * 262144;
#pragma unroll
    for (int mt = 0; mt < 2; mt++)
#pragma unroll
        for (int nt = 0; nt < 2; nt++) {
            int col = colBase + wn * 64 + nt * 32 + l31;
#pragma unroll
            for (int r = 0; r < 16; r++) {
                int row = rowBase + wm * 64 + mt * 32 + (r & 3) + 8 * (r >> 2) + 4 * hi;
                Pz[(long)row * 256 + col] = acc[mt][nt][r];
            }
        }
}

__global__ __launch_bounds__(256)
void embed_combine_kernel(const float* __restrict__ P, const float* __restrict__ eb,
                          float* __restrict__ e, int nsplit) {
    int idx = blockIdx.x * 256 + threadIdx.x;
    float s = 0.f;
    for (int z = 0; z < nsplit; z++) s += P[(long)z * 262144 + idx];
    e[idx] = s + eb[idx & 255];
}

// ---------------- fused zinit + layer-0 QKV (MFMA, packed fp16 weights) ----------------
__global__ __launch_bounds__(512)
void qkv_init_kernel(const float* __restrict__ e, const float* __restrict__ sc,
                     const float* __restrict__ sh, const short* __restrict__ lw0,
                     const float* __restrict__ bq0, const float* __restrict__ bk0,
                     const float* __restrict__ bv0,
                     float* __restrict__ z, float* __restrict__ qo,
                     float* __restrict__ ko, float* __restrict__ vo) {
    __shared__ _Float16 zsh[4][256], zsl[4][256];
    const int t = threadIdx.x;
    const int w = t >> 6, lane = t & 63;
    const long rowg0 = (long)blockIdx.x * 4;

    for (int idx = t; idx < 1024; idx += 512) {
        int i = idx >> 8, dd = idx & 255;
        int c = (int)((rowg0 + i) & 255);
        float v = fmaf(e[(rowg0 + i) * 256 + dd], sc[c], sh[c]);
        v = fmaxf(v, 0.f);
        int i2 = dd >> 1;
        float ang = (float)c * expf(-0.03597789207803195f * (float)(2 * i2));
        float pe = (dd & 1) ? cosf(ang) : sinf(ang);
        float zz = v + pe;
        z[(rowg0 + i) * 256 + dd] = zz;
        _Float16 hh, ll;
        f16split2(zz, hh, ll);
        zsh[i][dd] = hh; zsl[i][dd] = ll;
    }
    __syncthreads();

#pragma unroll
    for (int mat = 0; mat < 3; mat++) {
        const short* wp = lw0 + 65536 * (1 + mat);
        const float* bb = (mat == 0 ? bq0 : mat == 1 ? bk0 : bv0);
        float* op = (mat == 0 ? qo : mat == 1 ? ko : vo);
        for (int nt = w; nt < 16; nt += 8) {
            f32x4 acc = mfma_nt(&zsh[0][0], &zsl[0][0], 256, wp + nt * 8 * 512, 8, lane);
            if (lane < 16) {
                int col = nt * 16 + lane;
                float bv2 = bb[col];
#pragma unroll
                for (int r = 0; r < 4; r++)
                    op[(rowg0 + r) * 256 + col] = acc[r] + bv2;
            }
        }
    }
}

// ---------------- fused transformer layer: attention GEMV + MFMA projections ----------------
__device__ inline void ln_reduce4(const float (*buf)[256], float (*mr)[2], int t) {
    int wid = t >> 6, lane = t & 63;
    if (wid < 4) {
        float4 v = *(const float4*)&buf[wid][lane * 4];
        float s = v.x + v.y + v.z + v.w;
        float q = v.x * v.x + v.y * v.y + v.z * v.z + v.w * v.w;
#pragma unroll
        for (int off = 32; off > 0; off >>= 1) {
            s += __shfl_xor(s, off);
            q += __shfl_xor(q, off);
        }
        if (lane == 0) {
            float mean = s * (1.f / 256.f);
            float var = q * (1.f / 256.f) - mean * mean;
            mr[wid][0] = mean;
            mr[wid][1] = rsqrtf(var + 1e-5f);
        }
    }
}

template <int LAST>
__global__ __launch_bounds__(1024)
void layer_kernel(const float* __restrict__ zin, const float* __restrict__ qin,
                  const float* __restrict__ kin, const float* __restrict__ vin,
                  const short* __restrict__ lw_l, const short* __restrict__ lw_n,
                  const float* __restrict__ bo_l,
                  const float* __restrict__ c1b_l, const float* __restrict__ c2b_l,
                  const float* __restrict__ ln1g_l, const float* __restrict__ ln1b_l,
                  const float* __restrict__ ln2g_l, const float* __restrict__ ln2b_l,
                  const float* __restrict__ bq_n, const float* __restrict__ bk_n,
                  const float* __restrict__ bv_n,
                  const float* __restrict__ lnfg, const float* __restrict__ lnfb,
                  float* __restrict__ zout, float* __restrict__ qo,
                  float* __restrict__ ko, float* __restrict__ vo,
                  float* __restrict__ lnf_out) {
    __shared__ float zs[4][256];
    __shared__ float qb[4][256];
    __shared__ float sscore[4][8][256];
    __shared__ _Float16 zsh[4][256], zsl[4][256];
    __shared__ _Float16 yh[4][1024], yl[4][1024];
    __shared__ float mr[4][2];

    const int t = threadIdx.x;
    const int w = t >> 6, lane = t & 63;
    const long rowg0 = (long)blockIdx.x * 4;
    const int b = blockIdx.x >> 6;

    const int f = t & 255;       // output dim for 256-wide phases
    const int kq = t >> 8;       // row 0..3

    // P1: stage z (residual) and q rows
    {
        int r = t >> 8, dd = t & 255;
        zs[r][dd] = zin[(rowg0 + r) * 256 + dd];
        qb[r][dd] = qin[(rowg0 + r) * 256 + dd];
    }
    __syncthreads();

    // P2: scores — wave pair per head
    {
        const float scale = 0.17677669529663687f;
        const int jq = lane >> 3, li = lane & 7, d4 = li * 4;
        const int hh = w >> 1, jh = w & 1;
        const float* kb = kin + (long)b * 65536 + hh * 32 + d4;
        float4 q0 = *(const float4*)&qb[0][hh * 32 + d4];
        float4 q1 = *(const float4*)&qb[1][hh * 32 + d4];
        float4 q2 = *(const float4*)&qb[2][hh * 32 + d4];
        float4 q3 = *(const float4*)&qb[3][hh * 32 + d4];
        for (int jb = 0; jb < 16; jb++) {
            int j = jh * 128 + jb * 8 + jq;
            float4 kv = *(const float4*)(kb + (long)j * 256);
            float a0 = dot4(kv, q0), a1 = dot4(kv, q1);
            float a2 = dot4(kv, q2), a3 = dot4(kv, q3);
#pragma unroll
            for (int off = 1; off < 8; off <<= 1) {
                a0 += __shfl_xor(a0, off); a1 += __shfl_xor(a1, off);
                a2 += __shfl_xor(a2, off); a3 += __shfl_xor(a3, off);
            }
            if (li < 4) sscore[li][hh][j] = sel4(a0, a1, a2, a3, li) * scale;
        }
    }
    __syncthreads();

    // P3: softmax
    {
#pragma unroll
        for (int p = 0; p < 2; p++) {
            int pair = w * 2 + p;
            int i = pair >> 3, hh = pair & 7;
            float* row = sscore[i][hh];
            float v0 = row[lane], v1 = row[lane + 64];
            float v2 = row[lane + 128], v3 = row[lane + 192];
            float m = fmaxf(fmaxf(v0, v1), fmaxf(v2, v3));
#pragma unroll
            for (int off = 32; off > 0; off >>= 1) m = fmaxf(m, __shfl_xor(m, off));
            float e0 = expf(v0 - m), e1 = expf(v1 - m);
            float e2 = expf(v2 - m), e3 = expf(v3 - m);
            float su = e0 + e1 + e2 + e3;
#pragma unroll
            for (int off = 32; off > 0; off >>= 1) su += __shfl_xor(su, off);
            float inv = 1.f / su;
            row[lane] = e0 * inv; row[lane + 64] = e1 * inv;
            row[lane + 128] = e2 * inv; row[lane + 192] = e3 * inv;
        }
    }
    __syncthreads();

    // P4: PV — thread owns (f, row); write split attention output
    {
        int row = kq;
        int hh = f >> 5;
        const float* vcol = vin + (long)b * 65536 + f;
        const float* p0 = sscore[row][hh];
        float a0 = 0.f;
#pragma unroll 4
        for (int j4 = 0; j4 < 64; j4++) {
            float4 pv0 = *(const float4*)(p0 + j4 * 4);
            float v0 = vcol[(long)(j4 * 4 + 0) * 256];
            float v1 = vcol[(long)(j4 * 4 + 1) * 256];
            float v2 = vcol[(long)(j4 * 4 + 2) * 256];
            float v3 = vcol[(long)(j4 * 4 + 3) * 256];
            a0 = fmaf(pv0.x, v0, a0); a0 = fmaf(pv0.y, v1, a0);
            a0 = fmaf(pv0.z, v2, a0); a0 = fmaf(pv0.w, v3, a0);
        }
        _Float16 hh2, ll;
        f16split2(a0, hh2, ll);
        zsh[row][f] = hh2; zsl[row][f] = ll;
    }
    __syncthreads();

    // P5: O-proj MFMA + bias + residual -> qb
    {
        int nt = w;
        f32x4 acc = mfma_nt(&zsh[0][0], &zsl[0][0], 256, lw_l + nt * 8 * 512, 8, lane);
        if (lane < 16) {
            int col = nt * 16 + lane;
            float bb = bo_l[col];
#pragma unroll
            for (int r = 0; r < 4; r++)
                qb[r][col] = acc[r] + bb + zs[r][col];
        }
    }
    __syncthreads();
    ln_reduce4(qb, mr, t);
    __syncthreads();
    {
        int r = kq;
        float z1 = (qb[r][f] - mr[r][0]) * mr[r][1] * ln1g_l[f] + ln1b_l[f];
        zs[r][f] = z1;
        _Float16 hh2, ll;
        f16split2(z1, hh2, ll);
        zsh[r][f] = hh2; zsl[r][f] = ll;
    }
    __syncthreads();

    // P7: FFN1 MFMA + gelu -> yh/yl
    {
        const short* wp = lw_l + 262144;
        for (int nt = w; nt < 64; nt += 16) {
            f32x4 acc = mfma_nt(&zsh[0][0], &zsl[0][0], 256, wp + nt * 8 * 512, 8, lane);
            if (lane < 16) {
                int col = nt * 16 + lane;
                float cb = c1b_l[col];
#pragma unroll
                for (int r = 0; r < 4; r++) {
                    float g = gelu_f(acc[r] + cb);
                    _Float16 hh2, ll;
                    f16split2(g, hh2, ll);
                    yh[r][col] = hh2; yl[r][col] = ll;
                }
            }
        }
    }
    __syncthreads();

    // P8: FFN2 MFMA (K=1024) + bias + residual -> qb
    {
        const short* wp = lw_l + 524288;
        int nt = w;
        f32x4 acc = mfma_nt(&yh[0][0], &yl[0][0], 1024, wp + nt * 32 * 512, 32, lane);
        if (lane < 16) {
            int col = nt * 16 + lane;
            float cb = c2b_l[col];
#pragma unroll
            for (int r = 0; r < 4; r++)
                qb[r][col] = acc[r] + cb + zs[r][col];
        }
    }
    __syncthreads();
    ln_reduce4(qb, mr, t);
    __syncthreads();
    {
        int r = kq;
        float z2 = (qb[r][f] - mr[r][0]) * mr[r][1] * ln2g_l[f] + ln2b_l[f];
        zs[r][f] = z2;
        zout[(rowg0 + r) * 256 + f] = z2;
        _Float16 hh2, ll;
        f16split2(z2, hh2, ll);
        zsh[r][f] = hh2; zsl[r][f] = ll;
    }
    __syncthreads();

    if (!LAST) {
        // P9: QKV MFMA for next layer
#pragma unroll
        for (int mat = 0; mat < 3; mat++) {
            const short* wp = lw_n + 65536 * (1 + mat);
            const float* bb = (mat == 0 ? bq_n : mat == 1 ? bk_n : bv_n);
            float* op = (mat == 0 ? qo : mat == 1 ? ko : vo);
            int nt = w;
            f32x4 acc = mfma_nt(&zsh[0][0], &zsl[0][0], 256, wp + nt * 8 * 512, 8, lane);
            if (lane < 16) {
                int col = nt * 16 + lane;
                float bv2 = bb[col];
#pragma unroll
                for (int r = 0; r < 4; r++)
                    op[(rowg0 + r) * 256 + col] = acc[r] + bv2;
            }
        }
    } else {
        ln_reduce4(zs, mr, t);
        __syncthreads();
        {
            int r = kq;
            lnf_out[(rowg0 + r) * 256 + f] =
                (zs[r][f] - mr[r][0]) * mr[r][1] * lnfg[f] + lnfb[f];
        }
    }
}

// ---------------- final: pooled mean over seq -> proj ----------------
__global__ __launch_bounds__(256)
void final_kernel(const float* __restrict__ zf, const float* __restrict__ pw,
                  const float* __restrict__ pb, float* __restrict__ out) {
    __shared__ float sm[8];
    int b = blockIdx.x, d = threadIdx.x;
    float s = 0.f;
    for (int c = 0; c < 256; c++) s += zf[((long)(b * 256 + c)) * 256 + d];
    float pooled = s * (1.f / 256.f);
    float c0 = pooled * pw[d], c1 = pooled * pw[256 + d];
    for (int off = 32; off > 0; off >>= 1) { c0 += __shfl_down(c0, off); c1 += __shfl_down(c1, off); }
    int lane = d & 63, wv = d >> 6;
    if (lane == 0) { sm[wv] = c0; sm[4 + wv] = c1; }
    __syncthreads();
    if (d == 0) {
        out[b * 2 + 0] = sm[0] + sm[1] + sm[2] + sm[3] + pb[0];
        out[b * 2 + 1] = sm[4] + sm[5] + sm[6] + sm[7] + pb[1];
    }
}

extern "C" void kernel_launch(void* const* d_in, const int* in_sizes, int n_in,
                              void* d_out, int out_size, void* d_ws, size_t ws_size,
                              hipStream_t stream) {
    const float* x       = (const float*)d_in[0];
    const float* filters = (const float*)d_in[1];
    const float* bn1_g   = (const float*)d_in[2];
    const float* bn1_b   = (const float*)d_in[3];
    const float* emb_w   = (const float*)d_in[4];
    const float* emb_b   = (const float*)d_in[5];
    const float* embbn_g = (const float*)d_in[6];
    const float* embbn_b = (const float*)d_in[7];
    const float* wq      = (const float*)d_in[8];
    const float* bq      = (const float*)d_in[9];
    const float* wk      = (const float*)d_in[10];
    const float* bk      = (const float*)d_in[11];
    const float* wv      = (const float*)d_in[12];
    const float* bv      = (const float*)d_in[13];
    const float* wo      = (const float*)d_in[14];
    const float* bo      = (const float*)d_in[15];
    const float* c1w     = (const float*)d_in[16];
    const float* c1b     = (const float*)d_in[17];
    const float* c2w     = (const float*)d_in[18];
    const float* c2b     = (const float*)d_in[19];
    const float* ln1g    = (const float*)d_in[20];
    const float* ln1b    = (const float*)d_in[21];
    const float* ln2g    = (const float*)d_in[22];
    const float* ln2b    = (const float*)d_in[23];
    const float* lnfg    = (const float*)d_in[24];
    const float* lnfb    = (const float*)d_in[25];
    const float* projw   = (const float*)d_in[26];
    const float* projb   = (const float*)d_in[27];

    const long hF = 11005952L;                      // 1024*TPP halfs, in float units
    const long wpackF = 2752512L;                   // 8*NKC*512 shorts, in floats
    const long lwF = 1572864L;                      // 4*LWSZ shorts, in floats
    const long fixedF = hF + 5120 + wpackF + lwF + 9L * 262144;
    long wsFloats = (long)(ws_size / 4);
    long Z = 32;
    while (Z > 8 && fixedF + Z * 262144L > wsFloats) Z >>= 1;
    const int kPerZ = KEMBP / (int)Z;

    float* ws = (float*)d_ws;
    _Float16* h16 = (_Float16*)ws;                  // 1024*TPP halfs
    float* bn1_sc = ws + hF;
    float* bn1_sh = bn1_sc + 256;
    float* e_sc   = bn1_sh + 256;
    float* e_sh   = e_sc + 256;
    float* bnp1   = e_sh + 256;                     // 2048
    float* bnp2   = bnp1 + 2048;                    // 2048
    float* part   = bnp2 + 2048;                    // Z * 262144
    float* wsp    = part + Z * 262144L;
    short* wpH    = (short*)wsp;                    // 8*NKC*512 shorts
    float* e      = wsp + wpackF;
    float* z      = e + 262144;
    float* qA     = z + 262144;
    float* kA     = qA + 262144;
    float* vA     = kA + 262144;
    float* qB     = vA + 262144;
    float* kB     = qB + 262144;
    float* vB     = kB + 262144;
    float* t1     = vB + 262144;
    short* lw     = (short*)(t1 + 262144);          // 4*LWSZ shorts

    // conv packed filters alias onto `part` (only used before embed writes part)
    short* fpH = (short*)part;                      // 520*512 shorts

    filt_pack_kernel<<<520, 512, 0, stream>>>(filters, fpH);
    wpack_kernel<<<8 * NKC, 512, 0, stream>>>(emb_w, wpH);
    lwpack_kernel<<<6144, 512, 0, stream>>>(wo, wq, wk, wv, c1w, c2w, lw);
    conv_mfma_kernel<<<dim3(672, 4), 256, 0, stream>>>(x, fpH, h16);
    bn_part_kernel<<<dim3(256, 8), 256, 0, stream>>>(h16, bnp1, bnp2);
    bn_fin_kernel<<<1, 256, 0, stream>>>(bnp1, bnp2, bn1_g, bn1_b, bn1_sc, bn1_sh);
    embed_mfma_kernel<<<dim3(8, 2, (int)Z), 256, 0, stream>>>(h16, wpH,
                                                              bn1_sc, bn1_sh, part, kPerZ);
    embed_combine_kernel<<<1024, 256, 0, stream>>>(part, emb_b, e, (int)Z);
    bn_stats_kernel<<<256, 256, 0, stream>>>(e, embbn_g, embbn_b, e_sc, e_sh,
                                             256, 256L * 256);
    qkv_init_kernel<<<256, 512, 0, stream>>>(e, e_sc, e_sh, lw, bq, bk, bv,
                                             z, qA, kA, vA);

    float* qs[2][3] = {{qA, kA, vA}, {qB, kB, vB}};
    for (int l = 0; l < 4; l++) {
        float** in = qs[l & 1];
        float** ou = qs[(l + 1) & 1];
        const short* lw_l = lw + (long)l * LWSZ;
        const short* lw_n = lw + (long)((l + 1) & 3) * LWSZ;
        const float* bo_l = bo + l * 256;
        const float* c1b_l = c1b + l * 1024;
        const float* c2b_l = c2b + l * 256;
        const float* l1g = ln1g + l * 256; const float* l1b = ln1b + l * 256;
        const float* l2g = ln2g + l * 256; const float* l2b = ln2b + l * 256;
        if (l < 3) {
            const float* bq_n = bq + (l + 1) * 256;
            const float* bk_n = bk + (l + 1) * 256;
            const float* bv_n = bv + (l + 1) * 256;
            layer_kernel<0><<<256, 1024, 0, stream>>>(z, in[0], in[1], in[2],
                lw_l, lw_n, bo_l, c1b_l, c2b_l, l1g, l1b, l2g, l2b,
                bq_n, bk_n, bv_n, lnfg, lnfb,
                z, ou[0], ou[1], ou[2], t1);
        } else {
            layer_kernel<1><<<256, 1024, 0, stream>>>(z, in[0], in[1], in[2],
                lw_l, lw_n, bo_l, c1b_l, c2b_l, l1g, l1b, l2g, l2b,
                bq, bk, bv, lnfg, lnfb,
                z, ou[0], ou[1], ou[2], t1);
        }
    }

    final_kernel<<<4, 256, 0, stream>>>(t1, projw, projb, (float*)d_out);
}

// Round 14
// 461.799 us; speedup vs baseline: 5.8521x; 5.8521x over previous
//
#include <hip/hip_runtime.h>
#include <math.h>

#define L_IN 65494
#define T_POOL 21490
#define TPP 21496          // fp16 h row stride (16B-aligned rows)
#define KF 1025
#define RS 1144            // conv replica row stride (elements)
#define NCH 141            // 8-col chunks per replica row
#define KEMB 21490
#define KEMBP 21504        // padded
#define NKC 1344           // KEMBP/16
#define FTILE 33280        // 65*512 shorts per conv filter tile
#define LWSZ 786432        // packed layer-weight shorts per layer

typedef short s16x4 __attribute__((ext_vector_type(4)));
typedef _Float16 f16x8 __attribute__((ext_vector_type(8)));
typedef float f32x4 __attribute__((ext_vector_type(4)));
typedef float f32x16 __attribute__((ext_vector_type(16)));

__device__ inline float selu_f(float x) {
    float e = expf(fminf(x, 0.f));
    float neg = 1.6732632423543772f * (e - 1.f);
    return 1.0507009873554805f * (x > 0.f ? x : neg);
}

__device__ inline float gelu_f(float x) {
    return 0.5f * x * (1.f + erff(x * 0.7071067811865476f));
}

__device__ inline float dot4(float4 a, float4 b) {
    return fmaf(a.x, b.x, fmaf(a.y, b.y, fmaf(a.z, b.z, a.w * b.w)));
}

__device__ inline float sel4(float a0, float a1, float a2, float a3, int i) {
    float r = a0;
    r = (i == 1) ? a1 : r;
    r = (i == 2) ? a2 : r;
    r = (i == 3) ? a3 : r;
    return r;
}

__device__ inline short f2h_bits(float v) {
    _Float16 h = (_Float16)v;
    return *(short*)&h;
}

// x = hi + lo in fp16 (hi RTNE, lo = residual): exact to ~2^-22
__device__ inline void f16split(float v, short& hs, short& ls) {
    _Float16 h = (_Float16)v;
    float hf = (float)h;
    _Float16 l = (_Float16)(v - hf);
    hs = *(short*)&h;
    ls = *(short*)&l;
}

__device__ inline void f16split2(float v, _Float16& h, _Float16& l) {
    h = (_Float16)v;
    l = (_Float16)(v - (float)h);
}

// ---------------- filter pack: fp16 single, fragment-major [ft][kc][lane][8] ----------------
__global__ __launch_bounds__(512)
void filt_pack_kernel(const float* __restrict__ filt, short* __restrict__ fpH) {
    int blk = blockIdx.x;            // ft*65 + kc  (grid 520)
    int ft = blk / 65, kc = blk % 65;
    int t = threadIdx.x, lane = t >> 3, e = t & 7;
    int f = ft * 32 + (lane & 31);
    int tap = kc * 16 + (lane >> 5) * 8 + e;
    float v = (tap < KF) ? filt[f * KF + tap] : 0.f;
    fpH[blk * 512 + t] = f2h_bits(v);
}

// ---------------- emb_w pack: fp16 single, fragment-major [ft][kc][lane][8] ----------------
__global__ __launch_bounds__(512)
void wpack_kernel(const float* __restrict__ wsrc, short* __restrict__ wpH) {
    int blk = blockIdx.x;            // ft*NKC + kc  (grid 8*NKC)
    int ft = blk / NKC, kc = blk % NKC;
    int t = threadIdx.x, lane = t >> 3, e = t & 7;
    int row = ft * 32 + (lane & 31);
    int tap = kc * 16 + (lane >> 5) * 8 + e;
    float v = (tap < KEMB) ? wsrc[(long)row * KEMB + tap] : 0.f;
    wpH[(long)blk * 512 + t] = f2h_bits(v);
}

// ---------------- layer weight pack: fp16 fragment-major for 16x16x32 B-operand ----------------
__global__ __launch_bounds__(512)
void lwpack_kernel(const float* __restrict__ wo, const float* __restrict__ wq,
                   const float* __restrict__ wk, const float* __restrict__ wv,
                   const float* __restrict__ c1w, const float* __restrict__ c2w,
                   short* __restrict__ lw) {
    int b = blockIdx.x;              // grid 4*1536
    int layer = b / 1536, r = b % 1536;
    int t = threadIdx.x, lane = t >> 3, e = t & 7;
    const float* src;
    int K, t2;
    long dst;
    if (r < 512) {
        int mat = r >> 7; t2 = r & 127;
        const float* m0 = (mat == 0 ? wo : mat == 1 ? wq : mat == 2 ? wk : wv);
        src = m0 + (long)layer * 65536; K = 256;
        dst = (long)layer * LWSZ + (long)mat * 65536 + (long)t2 * 512;
    } else if (r < 1024) {
        t2 = r - 512;
        src = c1w + (long)layer * 262144; K = 256;
        dst = (long)layer * LWSZ + 262144 + (long)t2 * 512;
    } else {
        t2 = r - 1024;
        src = c2w + (long)layer * 262144; K = 1024;
        dst = (long)layer * LWSZ + 524288 + (long)t2 * 512;
    }
    int KB = K >> 5;
    int nt = t2 / KB, kb = t2 % KB;
    int n = nt * 16 + (lane & 15);
    int k = kb * 32 + ((lane >> 4) & 3) * 8 + e;
    lw[dst + t] = f2h_bits(src[(long)n * K + k]);
}

// ---------------- MFMA projection helper: one 16-col tile, M=16-padded (4 real rows) ----------
__device__ inline f32x4 mfma_nt(const _Float16* __restrict__ Xh, const _Float16* __restrict__ Xl,
                                int xstride, const short* __restrict__ wp_nt, int KB, int lane) {
    f32x4 acc = {0.f, 0.f, 0.f, 0.f};
    const int row = (lane & 15) & 3;
    const int ko0 = ((lane >> 4) & 3) * 8;
    const short* bp = wp_nt + lane * 8;
    const _Float16* xh = Xh + row * xstride + ko0;
    const _Float16* xl = Xl + row * xstride + ko0;
#pragma unroll 4
    for (int kb = 0; kb < KB; kb++) {
        f16x8 bf = *(const f16x8*)(bp + kb * 512);
        f16x8 ah = *(const f16x8*)(xh + kb * 32);
        f16x8 al = *(const f16x8*)(xl + kb * 32);
        acc = __builtin_amdgcn_mfma_f32_16x16x32_f16(al, bf, acc, 0, 0, 0);
        acc = __builtin_amdgcn_mfma_f32_16x16x32_f16(ah, bf, acc, 0, 0, 0);
    }
    return acc;
}

// ---------------- SincConv via MFMA (fp16 single-pass) + |.| + maxpool3 ----------------
union ConvLDS {
    short xh[8][RS];
    float ebuf[96][129];
};

#define MFMA2(ACC, AH, AL, BH) \
    ACC = __builtin_amdgcn_mfma_f32_32x32x16_f16(AL, BH, ACC, 0, 0, 0); \
    ACC = __builtin_amdgcn_mfma_f32_32x32x16_f16(AH, BH, ACC, 0, 0, 0);

__global__ __launch_bounds__(256, 3)
void conv_mfma_kernel(const float* __restrict__ x, const short* __restrict__ fpH,
                      _Float16* __restrict__ h) {
    __shared__ ConvLDS u;
    const int tid = threadIdx.x;
    const int pb = blockIdx.x;
    const int b = blockIdx.y;
    const int t0 = pb * 96;
    const float* xb = x + (long)b * L_IN;

    // staging: thread owns (replica s, 8-col chunk j); single fp16, b128 writes.
    if (pb < 671) {
        for (int idx = tid; idx < 8 * NCH; idx += 256) {
            int s = idx / NCH, j = idx - s * NCH;
            int gi = t0 + s + j * 8;
            f16x8 hv;
#pragma unroll
            for (int e = 0; e < 8; e++) hv[e] = (_Float16)xb[gi + e];
            *(f16x8*)&u.xh[s][j * 8] = hv;
        }
    } else {
        for (int idx = tid; idx < 8 * NCH; idx += 256) {
            int s = idx / NCH, j = idx - s * NCH;
            int gi = t0 + s + j * 8;
            f16x8 hv;
#pragma unroll
            for (int e = 0; e < 8; e++) {
                float v = (gi + e < L_IN) ? xb[gi + e] : 0.f;
                hv[e] = (_Float16)v;
            }
            *(f16x8*)&u.xh[s][j * 8] = hv;
        }
    }
    __syncthreads();

    const int lane = tid & 63;
    const int wid = tid >> 6;
    const int l31 = lane & 31;
    const int hi = lane >> 5;
    const int f0w = wid * 64;

    const short* aH = &u.xh[l31 & 7][8 * (l31 >> 3) + 8 * hi];
    const short* bp0 = fpH + (long)(wid * 2) * FTILE + lane * 8;
    const short* bp1 = bp0 + FTILE;

    f32x16 a00 = {0}, a01 = {0}, a10 = {0}, a11 = {0}, a20 = {0}, a21 = {0};

#pragma unroll 1
    for (int kc = 0; kc < 65; kc++) {
        const int ko = kc * 16;
        const int kf = kc * 512;
        f16x8 ah0 = *(const f16x8*)(aH + ko);
        f16x8 ah1 = *(const f16x8*)(aH + ko + 32);
        f16x8 ah2 = *(const f16x8*)(aH + ko + 64);
        f16x8 bh0 = *(const f16x8*)(bp0 + kf);
        f16x8 bh1 = *(const f16x8*)(bp1 + kf);
        a00 = __builtin_amdgcn_mfma_f32_32x32x16_f16(ah0, bh0, a00, 0, 0, 0);
        a01 = __builtin_amdgcn_mfma_f32_32x32x16_f16(ah0, bh1, a01, 0, 0, 0);
        a10 = __builtin_amdgcn_mfma_f32_32x32x16_f16(ah1, bh0, a10, 0, 0, 0);
        a11 = __builtin_amdgcn_mfma_f32_32x32x16_f16(ah1, bh1, a11, 0, 0, 0);
        a20 = __builtin_amdgcn_mfma_f32_32x32x16_f16(ah2, bh0, a20, 0, 0, 0);
        a21 = __builtin_amdgcn_mfma_f32_32x32x16_f16(ah2, bh1, a21, 0, 0, 0);
    }

    __syncthreads();
    const int t3l = tid & 31;
    const int t3 = pb * 32 + t3l;

#pragma unroll
    for (int half = 0; half < 2; half++) {
        if ((wid >> 1) == half) {
            int fcb = f0w - half * 128;
#define WRF(ACC, MT, NT)                                                   \
            {                                                              \
                int fc = fcb + NT * 32 + l31;                              \
                _Pragma("unroll")                                          \
                for (int r = 0; r < 16; r++) {                             \
                    int pos = MT * 32 + (r & 3) + 8 * (r >> 2) + 4 * hi;   \
                    u.ebuf[pos][fc] = fabsf(ACC[r]);                       \
                }                                                          \
            }
            WRF(a00, 0, 0) WRF(a01, 0, 1)
            WRF(a10, 1, 0) WRF(a11, 1, 1)
            WRF(a20, 2, 0) WRF(a21, 2, 1)
#undef WRF
        }
        __syncthreads();
        if (t3 < T_POOL) {
            for (int ff = tid >> 5; ff < 128; ff += 8) {
                float v = fmaxf(fmaxf(u.ebuf[3 * t3l][ff], u.ebuf[3 * t3l + 1][ff]),
                                u.ebuf[3 * t3l + 2][ff]);
                h[((long)(b * 256 + half * 128 + ff)) * TPP + t3] = (_Float16)v;
            }
        }
        __syncthreads();
    }
}

// ---------------- BatchNorm stats for h (fp16): two-stage ----------------
__global__ __launch_bounds__(256)
void bn_part_kernel(const _Float16* __restrict__ xin, float* __restrict__ p1,
                    float* __restrict__ p2) {
    __shared__ float sm[8];
    int c = blockIdx.x, s = blockIdx.y, tid = threadIdx.x;
    int t0 = s * 2687, t1 = min(T_POOL, t0 + 2687);
    float s1 = 0.f, s2 = 0.f;
    for (int b = 0; b < 4; b++) {
        const _Float16* p = xin + (long)b * 256 * TPP + (long)c * TPP;
        for (int t = t0 + tid; t < t1; t += 256) {
            float v = (float)p[t];
            s1 += v;
            s2 = fmaf(v, v, s2);
        }
    }
    for (int off = 32; off > 0; off >>= 1) { s1 += __shfl_down(s1, off); s2 += __shfl_down(s2, off); }
    int lane = tid & 63, wv = tid >> 6;
    if (lane == 0) { sm[wv] = s1; sm[4 + wv] = s2; }
    __syncthreads();
    if (tid == 0) {
        p1[c * 8 + s] = sm[0] + sm[1] + sm[2] + sm[3];
        p2[c * 8 + s] = sm[4] + sm[5] + sm[6] + sm[7];
    }
}

__global__ __launch_bounds__(256)
void bn_fin_kernel(const float* __restrict__ p1, const float* __restrict__ p2,
                   const float* __restrict__ g, const float* __restrict__ bb,
                   float* __restrict__ sc, float* __restrict__ sh) {
    int c = threadIdx.x;
    float S1 = 0.f, S2 = 0.f;
#pragma unroll
    for (int s = 0; s < 8; s++) { S1 += p1[c * 8 + s]; S2 += p2[c * 8 + s]; }
    float n = 4.f * (float)T_POOL;
    float mean = S1 / n;
    float var = S2 / n - mean * mean;
    float rstd = rsqrtf(var + 1e-5f);
    float gc = g[c], bc = bb[c];
    sc[c] = rstd * gc;
    sh[c] = bc - mean * rstd * gc;
}

// ---------------- BatchNorm stats (small, for e) ----------------
__global__ __launch_bounds__(256)
void bn_stats_kernel(const float* __restrict__ xin, const float* __restrict__ g,
                     const float* __restrict__ bb, float* __restrict__ sc,
                     float* __restrict__ sh, int ilen, long bstride) {
    __shared__ float sm[8];
    int c = blockIdx.x, tid = threadIdx.x;
    float s1 = 0.f, s2 = 0.f;
    for (int b = 0; b < 4; b++) {
        const float* p = xin + b * bstride + (long)c * ilen;
        for (int t = tid; t < ilen; t += 256) {
            float v = p[t];
            s1 += v;
            s2 = fmaf(v, v, s2);
        }
    }
    for (int off = 32; off > 0; off >>= 1) { s1 += __shfl_down(s1, off); s2 += __shfl_down(s2, off); }
    int lane = tid & 63, wv = tid >> 6;
    if (lane == 0) { sm[wv] = s1; sm[4 + wv] = s2; }
    __syncthreads();
    if (tid == 0) {
        float S1 = sm[0] + sm[1] + sm[2] + sm[3];
        float S2 = sm[4] + sm[5] + sm[6] + sm[7];
        float n = 4.f * (float)ilen;
        float mean = S1 / n;
        float var = S2 / n - mean * mean;
        float rstd = rsqrtf(var + 1e-5f);
        float gc = g[c], bc = bb[c];
        sc[c] = rstd * gc;
        sh[c] = bc - mean * rstd * gc;
    }
}

// ---------------- Embedding GEMM via MFMA (fp16 2-pass), split-K, packed B ----------------
__global__ __launch_bounds__(256, 2)
void embed_mfma_kernel(const _Float16* __restrict__ H, const short* __restrict__ Wh,
                       const float* __restrict__ sc, const float* __restrict__ sh,
                       float* __restrict__ P, int kPerZ) {
    __shared__ short Ah[128][36];
    __shared__ short Al[128][36];
    const int tid = threadIdx.x;
    const int rowBase = blockIdx.x * 128;
    const int colBase = blockIdx.y * 128;
    const int z = blockIdx.z;
    const int kz = z * kPerZ;
    const int iters = kPerZ >> 5;

    const int trow = tid >> 1, th = (tid & 1) * 16;
    const int arow = rowBase + trow;
    const float asc = sc[arow & 255], ash_ = sh[arow & 255];
    const _Float16* Ap = H + (long)arow * TPP;

    const int lane = tid & 63, wid = tid >> 6;
    const int l31 = lane & 31, hi = lane >> 5;
    const int wm = wid >> 1, wn = wid & 1;

    const short* bhp[2];
#pragma unroll
    for (int nt = 0; nt < 2; nt++) {
        int ft = (colBase >> 5) + wn * 2 + nt;
        bhp[nt] = Wh + (long)ft * NKC * 512 + lane * 8;
    }

    f32x16 acc[2][2] = {{{0}, {0}}, {{0}, {0}}};

    for (int it = 0; it < iters; it++) {
        const int k0 = kz + it * 32;
        __syncthreads();
        float av[16];
        if (k0 + 32 <= KEMB) {
            const f16x8* p8 = (const f16x8*)(Ap + k0 + th);
            f16x8 v0 = p8[0], v1 = p8[1];
#pragma unroll
            for (int e = 0; e < 8; e++) { av[e] = (float)v0[e]; av[8 + e] = (float)v1[e]; }
        } else {
#pragma unroll
            for (int e = 0; e < 16; e++) {
                int k = k0 + th + e;
                av[e] = (k < KEMB) ? (float)Ap[k] : 0.f;
            }
        }
#pragma unroll
        for (int q = 0; q < 4; q++) {
            s16x4 h4, l4;
#pragma unroll
            for (int e = 0; e < 4; e++) {
                float v = selu_f(fmaf(av[q * 4 + e], asc, ash_));
                short hs, ls;
                f16split(v, hs, ls);
                h4[e] = hs; l4[e] = ls;
            }
            *(s16x4*)&Ah[trow][th + q * 4] = h4;
            *(s16x4*)&Al[trow][th + q * 4] = l4;
        }
        __syncthreads();

#pragma unroll
        for (int ks = 0; ks < 2; ks++) {
            const int kloc = ks * 16 + hi * 8;
            const long kcg = (long)((k0 >> 4) + ks) * 512;
            f16x8 ah[2], al[2], bh[2];
#pragma unroll
            for (int mt = 0; mt < 2; mt++) {
                const int r = wm * 64 + mt * 32 + l31;
                const short* ph = &Ah[r][kloc];
                const short* pl = &Al[r][kloc];
                union { f16x8 v; unsigned long long q[2]; } uh, ul;
                uh.q[0] = *(const unsigned long long*)(ph);
                uh.q[1] = *(const unsigned long long*)(ph + 4);
                ul.q[0] = *(const unsigned long long*)(pl);
                ul.q[1] = *(const unsigned long long*)(pl + 4);
                ah[mt] = uh.v; al[mt] = ul.v;
            }
#pragma unroll
            for (int nt = 0; nt < 2; nt++)
                bh[nt] = *(const f16x8*)(bhp[nt] + kcg);
#pragma unroll
            for (int mt = 0; mt < 2; mt++)
#pragma unroll
                for (int nt = 0; nt < 2; nt++) {
                    MFMA2(acc[mt][nt], ah[mt], al[mt], bh[nt])
                }
        }
    }

    float* Pz = P + (long)z * 262144;
#pragma unroll
    for (int mt = 0; mt < 2; mt++)
#pragma unroll
        for (int nt = 0; nt < 2; nt++) {
            int col = colBase + wn * 64 + nt * 32 + l31;
#pragma unroll
            for (int r = 0; r < 16; r++) {
                int row = rowBase + wm * 64 + mt * 32 + (r & 3) + 8 * (r >> 2) + 4 * hi;
                Pz[(long)row * 256 + col] = acc[mt][nt][r];
            }
        }
}

__global__ __launch_bounds__(256)
void embed_combine_kernel(const float* __restrict__ P, const float* __restrict__ eb,
                          float* __restrict__ e, int nsplit) {
    int idx = blockIdx.x * 256 + threadIdx.x;
    float s = 0.f;
    for (int z = 0; z < nsplit; z++) s += P[(long)z * 262144 + idx];
    e[idx] = s + eb[idx & 255];
}

// ---------------- fused zinit + layer-0 QKV (MFMA, packed fp16 weights) ----------------
__global__ __launch_bounds__(512)
void qkv_init_kernel(const float* __restrict__ e, const float* __restrict__ sc,
                     const float* __restrict__ sh, const short* __restrict__ lw0,
                     const float* __restrict__ bq0, const float* __restrict__ bk0,
                     const float* __restrict__ bv0,
                     float* __restrict__ z, float* __restrict__ qo,
                     float* __restrict__ ko, float* __restrict__ vo) {
    __shared__ _Float16 zsh[4][256], zsl[4][256];
    const int t = threadIdx.x;
    const int w = t >> 6, lane = t & 63;
    const long rowg0 = (long)blockIdx.x * 4;

    for (int idx = t; idx < 1024; idx += 512) {
        int i = idx >> 8, dd = idx & 255;
        int c = (int)((rowg0 + i) & 255);
        float v = fmaf(e[(rowg0 + i) * 256 + dd], sc[c], sh[c]);
        v = fmaxf(v, 0.f);
        int i2 = dd >> 1;
        float ang = (float)c * expf(-0.03597789207803195f * (float)(2 * i2));
        float pe = (dd & 1) ? cosf(ang) : sinf(ang);
        float zz = v + pe;
        z[(rowg0 + i) * 256 + dd] = zz;
        _Float16 hh, ll;
        f16split2(zz, hh, ll);
        zsh[i][dd] = hh; zsl[i][dd] = ll;
    }
    __syncthreads();

#pragma unroll
    for (int mat = 0; mat < 3; mat++) {
        const short* wp = lw0 + 65536 * (1 + mat);
        const float* bb = (mat == 0 ? bq0 : mat == 1 ? bk0 : bv0);
        float* op = (mat == 0 ? qo : mat == 1 ? ko : vo);
        for (int nt = w; nt < 16; nt += 8) {
            f32x4 acc = mfma_nt(&zsh[0][0], &zsl[0][0], 256, wp + nt * 8 * 512, 8, lane);
            if (lane < 16) {
                int col = nt * 16 + lane;
                float bv2 = bb[col];
#pragma unroll
                for (int r = 0; r < 4; r++)
                    op[(rowg0 + r) * 256 + col] = acc[r] + bv2;
            }
        }
    }
}

// ---------------- fused transformer layer: attention GEMV + MFMA projections ----------------
__device__ inline void ln_reduce4(const float (*buf)[256], float (*mr)[2], int t) {
    int wid = t >> 6, lane = t & 63;
    if (wid < 4) {
        float4 v = *(const float4*)&buf[wid][lane * 4];
        float s = v.x + v.y + v.z + v.w;
        float q = v.x * v.x + v.y * v.y + v.z * v.z + v.w * v.w;
#pragma unroll
        for (int off = 32; off > 0; off >>= 1) {
            s += __shfl_xor(s, off);
            q += __shfl_xor(q, off);
        }
        if (lane == 0) {
            float mean = s * (1.f / 256.f);
            float var = q * (1.f / 256.f) - mean * mean;
            mr[wid][0] = mean;
            mr[wid][1] = rsqrtf(var + 1e-5f);
        }
    }
}

template <int LAST>
__global__ __launch_bounds__(1024)
void layer_kernel(const float* __restrict__ zin, const float* __restrict__ qin,
                  const float* __restrict__ kin, const float* __restrict__ vin,
                  const short* __restrict__ lw_l, const short* __restrict__ lw_n,
                  const float* __restrict__ bo_l,
                  const float* __restrict__ c1b_l, const float* __restrict__ c2b_l,
                  const float* __restrict__ ln1g_l, const float* __restrict__ ln1b_l,
                  const float* __restrict__ ln2g_l, const float* __restrict__ ln2b_l,
                  const float* __restrict__ bq_n, const float* __restrict__ bk_n,
                  const float* __restrict__ bv_n,
                  const float* __restrict__ lnfg, const float* __restrict__ lnfb,
                  float* __restrict__ zout, float* __restrict__ qo,
                  float* __restrict__ ko, float* __restrict__ vo,
                  float* __restrict__ lnf_out) {
    __shared__ float zs[4][256];
    __shared__ float qb[4][256];
    __shared__ float sscore[4][8][256];
    __shared__ _Float16 zsh[4][256], zsl[4][256];
    __shared__ _Float16 yh[4][1024], yl[4][1024];
    __shared__ float mr[4][2];

    const int t = threadIdx.x;
    const int w = t >> 6, lane = t & 63;
    const long rowg0 = (long)blockIdx.x * 4;
    const int b = blockIdx.x >> 6;

    const int f = t & 255;       // output dim for 256-wide phases
    const int kq = t >> 8;       // row 0..3

    // P1: stage z (residual) and q rows
    {
        int r = t >> 8, dd = t & 255;
        zs[r][dd] = zin[(rowg0 + r) * 256 + dd];
        qb[r][dd] = qin[(rowg0 + r) * 256 + dd];
    }
    __syncthreads();

    // P2: scores — wave pair per head
    {
        const float scale = 0.17677669529663687f;
        const int jq = lane >> 3, li = lane & 7, d4 = li * 4;
        const int hh = w >> 1, jh = w & 1;
        const float* kb = kin + (long)b * 65536 + hh * 32 + d4;
        float4 q0 = *(const float4*)&qb[0][hh * 32 + d4];
        float4 q1 = *(const float4*)&qb[1][hh * 32 + d4];
        float4 q2 = *(const float4*)&qb[2][hh * 32 + d4];
        float4 q3 = *(const float4*)&qb[3][hh * 32 + d4];
        for (int jb = 0; jb < 16; jb++) {
            int j = jh * 128 + jb * 8 + jq;
            float4 kv = *(const float4*)(kb + (long)j * 256);
            float a0 = dot4(kv, q0), a1 = dot4(kv, q1);
            float a2 = dot4(kv, q2), a3 = dot4(kv, q3);
#pragma unroll
            for (int off = 1; off < 8; off <<= 1) {
                a0 += __shfl_xor(a0, off); a1 += __shfl_xor(a1, off);
                a2 += __shfl_xor(a2, off); a3 += __shfl_xor(a3, off);
            }
            if (li < 4) sscore[li][hh][j] = sel4(a0, a1, a2, a3, li) * scale;
        }
    }
    __syncthreads();

    // P3: softmax
    {
#pragma unroll
        for (int p = 0; p < 2; p++) {
            int pair = w * 2 + p;
            int i = pair >> 3, hh = pair & 7;
            float* row = sscore[i][hh];
            float v0 = row[lane], v1 = row[lane + 64];
            float v2 = row[lane + 128], v3 = row[lane + 192];
            float m = fmaxf(fmaxf(v0, v1), fmaxf(v2, v3));
#pragma unroll
            for (int off = 32; off > 0; off >>= 1) m = fmaxf(m, __shfl_xor(m, off));
            float e0 = expf(v0 - m), e1 = expf(v1 - m);
            float e2 = expf(v2 - m), e3 = expf(v3 - m);
            float su = e0 + e1 + e2 + e3;
#pragma unroll
            for (int off = 32; off > 0; off >>= 1) su += __shfl_xor(su, off);
            float inv = 1.f / su;
            row[lane] = e0 * inv; row[lane + 64] = e1 * inv;
            row[lane + 128] = e2 * inv; row[lane + 192] = e3 * inv;
        }
    }
    __syncthreads();

    // P4: PV — thread owns (f, row); write split attention output
    {
        int row = kq;
        int hh = f >> 5;
        const float* vcol = vin + (long)b * 65536 + f;
        const float* p0 = sscore[row][hh];
        float a0 = 0.f;
#pragma unroll 4
        for (int j4 = 0; j4 < 64; j4++) {
            float4 pv0 = *(const float4*)(p0 + j4 * 4);
            float v0 = vcol[(long)(j4 * 4 + 0) * 256];
            float v1 = vcol[(long)(j4 * 4 + 1) * 256];
            float v2 = vcol[(long)(j4 * 4 + 2) * 256];
            float v3 = vcol[(long)(j4 * 4 + 3) * 256];
            a0 = fmaf(pv0.x, v0, a0); a0 = fmaf(pv0.y, v1, a0);
            a0 = fmaf(pv0.z, v2, a0); a0 = fmaf(pv0.w, v3, a0);
        }
        _Float16 hh2, ll;
        f16split2(a0, hh2, ll);
        zsh[row][f] = hh2; zsl[row][f] = ll;
    }
    __syncthreads();

    // P5: O-proj MFMA + bias + residual -> qb
    {
        int nt = w;
        f32x4 acc = mfma_nt(&zsh[0][0], &zsl[0][0], 256, lw_l + nt * 8 * 512, 8, lane);
        if (lane < 16) {
            int col = nt * 16 + lane;
            float bb = bo_l[col];
#pragma unroll
            for (int r = 0; r < 4; r++)
                qb[r][col] = acc[r] + bb + zs[r][col];
        }
    }
    __syncthreads();
    ln_reduce4(qb, mr, t);
    __syncthreads();
    {
        int r = kq;
        float z1 = (qb[r][f] - mr[r][0]) * mr[r][1] * ln1g_l[f] + ln1b_l[f];
        zs[r][f] = z1;
        _Float16 hh2, ll;
        f16split2(z1, hh2, ll);
        zsh[r][f] = hh2; zsl[r][f] = ll;
    }
    __syncthreads();

    // P7: FFN1 MFMA + gelu -> yh/yl
    {
        const short* wp = lw_l + 262144;
        for (int nt = w; nt < 64; nt += 16) {
            f32x4 acc = mfma_nt(&zsh[0][0], &zsl[0][0], 256, wp + nt * 8 * 512, 8, lane);
            if (lane < 16) {
                int col = nt * 16 + lane;
                float cb = c1b_l[col];
#pragma unroll
                for (int r = 0; r < 4; r++) {
                    float g = gelu_f(acc[r] + cb);
                    _Float16 hh2, ll;
                    f16split2(g, hh2, ll);
                    yh[r][col] = hh2; yl[r][col] = ll;
                }
            }
        }
    }
    __syncthreads();

    // P8: FFN2 MFMA (K=1024) + bias + residual -> qb
    {
        const short* wp = lw_l + 524288;
        int nt = w;
        f32x4 acc = mfma_nt(&yh[0][0], &yl[0][0], 1024, wp + nt * 32 * 512, 32, lane);
        if (lane < 16) {
            int col = nt * 16 + lane;
            float cb = c2b_l[col];
#pragma unroll
            for (int r = 0; r < 4; r++)
                qb[r][col] = acc[r] + cb + zs[r][col];
        }
    }
    __syncthreads();
    ln_reduce4(qb, mr, t);
    __syncthreads();
    {
        int r = kq;
        float z2 = (qb[r][f] - mr[r][0]) * mr[r][1] * ln2g_l[f] + ln2b_l[f];
        zs[r][f] = z2;
        zout[(rowg0 + r) * 256 + f] = z2;
        _Float16 hh2, ll;
        f16split2(z2, hh2, ll);
        zsh[r][f] = hh2; zsl[r][f] = ll;
    }
    __syncthreads();

    if (!LAST) {
        // P9: QKV MFMA for next layer
#pragma unroll
        for (int mat = 0; mat < 3; mat++) {
            const short* wp = lw_n + 65536 * (1 + mat);
            const float* bb = (mat == 0 ? bq_n : mat == 1 ? bk_n : bv_n);
            float* op = (mat == 0 ? qo : mat == 1 ? ko : vo);
            int nt = w;
            f32x4 acc = mfma_nt(&zsh[0][0], &zsl[0][0], 256, wp + nt * 8 * 512, 8, lane);
            if (lane < 16) {
                int col = nt * 16 + lane;
                float bv2 = bb[col];
#pragma unroll
                for (int r = 0; r < 4; r++)
                    op[(rowg0 + r) * 256 + col] = acc[r] + bv2;
            }
        }
    } else {
        ln_reduce4(zs, mr, t);
        __syncthreads();
        {
            int r = kq;
            lnf_out[(rowg0 + r) * 256 + f] =
                (zs[r][f] - mr[r][0]) * mr[r][1] * lnfg[f] + lnfb[f];
        }
    }
}

// ---------------- final: pooled mean over seq -> proj ----------------
__global__ __launch_bounds__(256)
void final_kernel(const float* __restrict__ zf, const float* __restrict__ pw,
                  const float* __restrict__ pb, float* __restrict__ out) {
    __shared__ float sm[8];
    int b = blockIdx.x, d = threadIdx.x;
    float s = 0.f;
    for (int c = 0; c < 256; c++) s += zf[((long)(b * 256 + c)) * 256 + d];
    float pooled = s * (1.f / 256.f);
    float c0 = pooled * pw[d], c1 = pooled * pw[256 + d];
    for (int off = 32; off > 0; off >>= 1) { c0 += __shfl_down(c0, off); c1 += __shfl_down(c1, off); }
    int lane = d & 63, wv = d >> 6;
    if (lane == 0) { sm[wv] = c0; sm[4 + wv] = c1; }
    __syncthreads();
    if (d == 0) {
        out[b * 2 + 0] = sm[0] + sm[1] + sm[2] + sm[3] + pb[0];
        out[b * 2 + 1] = sm[4] + sm[5] + sm[6] + sm[7] + pb[1];
    }
}

extern "C" void kernel_launch(void* const* d_in, const int* in_sizes, int n_in,
                              void* d_out, int out_size, void* d_ws, size_t ws_size,
                              hipStream_t stream) {
    const float* x       = (const float*)d_in[0];
    const float* filters = (const float*)d_in[1];
    const float* bn1_g   = (const float*)d_in[2];
    const float* bn1_b   = (const float*)d_in[3];
    const float* emb_w   = (const float*)d_in[4];
    const float* emb_b   = (const float*)d_in[5];
    const float* embbn_g = (const float*)d_in[6];
    const float* embbn_b = (const float*)d_in[7];
    const float* wq      = (const float*)d_in[8];
    const float* bq      = (const float*)d_in[9];
    const float* wk      = (const float*)d_in[10];
    const float* bk      = (const float*)d_in[11];
    const float* wv      = (const float*)d_in[12];
    const float* bv      = (const float*)d_in[13];
    const float* wo      = (const float*)d_in[14];
    const float* bo      = (const float*)d_in[15];
    const float* c1w     = (const float*)d_in[16];
    const float* c1b     = (const float*)d_in[17];
    const float* c2w     = (const float*)d_in[18];
    const float* c2b     = (const float*)d_in[19];
    const float* ln1g    = (const float*)d_in[20];
    const float* ln1b    = (const float*)d_in[21];
    const float* ln2g    = (const float*)d_in[22];
    const float* ln2b    = (const float*)d_in[23];
    const float* lnfg    = (const float*)d_in[24];
    const float* lnfb    = (const float*)d_in[25];
    const float* projw   = (const float*)d_in[26];
    const float* projb   = (const float*)d_in[27];

    const long hF = 11005952L;                      // 1024*TPP halfs, in float units
    const long wpackF = 2752512L;                   // 8*NKC*512 shorts, in floats
    const long lwF = 1572864L;                      // 4*LWSZ shorts, in floats
    const long fixedF = hF + 5120 + wpackF + lwF + 9L * 262144;
    long wsFloats = (long)(ws_size / 4);
    long Z = 32;
    while (Z > 8 && fixedF + Z * 262144L > wsFloats) Z >>= 1;
    const int kPerZ = KEMBP / (int)Z;

    float* ws = (float*)d_ws;
    _Float16* h16 = (_Float16*)ws;                  // 1024*TPP halfs
    float* bn1_sc = ws + hF;
    float* bn1_sh = bn1_sc + 256;
    float* e_sc   = bn1_sh + 256;
    float* e_sh   = e_sc + 256;
    float* bnp1   = e_sh + 256;                     // 2048
    float* bnp2   = bnp1 + 2048;                    // 2048
    float* part   = bnp2 + 2048;                    // Z * 262144
    float* wsp    = part + Z * 262144L;
    short* wpH    = (short*)wsp;                    // 8*NKC*512 shorts
    float* e      = wsp + wpackF;
    float* z      = e + 262144;
    float* qA     = z + 262144;
    float* kA     = qA + 262144;
    float* vA     = kA + 262144;
    float* qB     = vA + 262144;
    float* kB     = qB + 262144;
    float* vB     = kB + 262144;
    float* t1     = vB + 262144;
    short* lw     = (short*)(t1 + 262144);          // 4*LWSZ shorts

    // conv packed filters alias onto `part` (only used before embed writes part)
    short* fpH = (short*)part;                      // 520*512 shorts

    filt_pack_kernel<<<520, 512, 0, stream>>>(filters, fpH);
    wpack_kernel<<<8 * NKC, 512, 0, stream>>>(emb_w, wpH);
    lwpack_kernel<<<6144, 512, 0, stream>>>(wo, wq, wk, wv, c1w, c2w, lw);
    conv_mfma_kernel<<<dim3(672, 4), 256, 0, stream>>>(x, fpH, h16);
    bn_part_kernel<<<dim3(256, 8), 256, 0, stream>>>(h16, bnp1, bnp2);
    bn_fin_kernel<<<1, 256, 0, stream>>>(bnp1, bnp2, bn1_g, bn1_b, bn1_sc, bn1_sh);
    embed_mfma_kernel<<<dim3(8, 2, (int)Z), 256, 0, stream>>>(h16, wpH,
                                                              bn1_sc, bn1_sh, part, kPerZ);
    embed_combine_kernel<<<1024, 256, 0, stream>>>(part, emb_b, e, (int)Z);
    bn_stats_kernel<<<256, 256, 0, stream>>>(e, embbn_g, embbn_b, e_sc, e_sh,
                                             256, 256L * 256);
    qkv_init_kernel<<<256, 512, 0, stream>>>(e, e_sc, e_sh, lw, bq, bk, bv,
                                             z, qA, kA, vA);

    float* qs[2][3] = {{qA, kA, vA}, {qB, kB, vB}};
    for (int l = 0; l < 4; l++) {
        float** in = qs[l & 1];
        float** ou = qs[(l + 1) & 1];
        const short* lw_l = lw + (long)l * LWSZ;
        const short* lw_n = lw + (long)((l + 1) & 3) * LWSZ;
        const float* bo_l = bo + l * 256;
        const float* c1b_l = c1b + l * 1024;
        const float* c2b_l = c2b + l * 256;
        const float* l1g = ln1g + l * 256; const float* l1b = ln1b + l * 256;
        const float* l2g = ln2g + l * 256; const float* l2b = ln2b + l * 256;
        if (l < 3) {
            const float* bq_n = bq + (l + 1) * 256;
            const float* bk_n = bk + (l + 1) * 256;
            const float* bv_n = bv + (l + 1) * 256;
            layer_kernel<0><<<256, 1024, 0, stream>>>(z, in[0], in[1], in[2],
                lw_l, lw_n, bo_l, c1b_l, c2b_l, l1g, l1b, l2g, l2b,
                bq_n, bk_n, bv_n, lnfg, lnfb,
                z, ou[0], ou[1], ou[2], t1);
        } else {
            layer_kernel<1><<<256, 1024, 0, stream>>>(z, in[0], in[1], in[2],
                lw_l, lw_n, bo_l, c1b_l, c2b_l, l1g, l1b, l2g, l2b,
                bq, bk, bv, lnfg, lnfb,
                z, ou[0], ou[1], ou[2], t1);
        }
    }

    final_kernel<<<4, 256, 0, stream>>>(t1, projw, projb, (float*)d_out);
}

// Round 15
// 450.485 us; speedup vs baseline: 5.9991x; 1.0251x over previous
//
#include <hip/hip_runtime.h>
#include <math.h>

#define L_IN 65494
#define T_POOL 21490
#define TPP 21496          // fp16 h row stride (16B-aligned rows)
#define KF 1025
#define RS 1144            // conv replica row stride (elements)
#define NCH 141            // 8-col chunks per replica row
#define KEMB 21490
#define KEMBP 21504        // padded
#define NKC 1344           // KEMBP/16
#define FTILE 33280        // 65*512 shorts per conv filter tile
#define LWSZ 786432        // packed layer-weight shorts per layer

typedef short s16x4 __attribute__((ext_vector_type(4)));
typedef _Float16 f16x8 __attribute__((ext_vector_type(8)));
typedef float f32x4 __attribute__((ext_vector_type(4)));
typedef float f32x16 __attribute__((ext_vector_type(16)));

__device__ inline float selu_f(float x) {
    float e = expf(fminf(x, 0.f));
    float neg = 1.6732632423543772f * (e - 1.f);
    return 1.0507009873554805f * (x > 0.f ? x : neg);
}

__device__ inline float gelu_f(float x) {
    return 0.5f * x * (1.f + erff(x * 0.7071067811865476f));
}

__device__ inline float dot4(float4 a, float4 b) {
    return fmaf(a.x, b.x, fmaf(a.y, b.y, fmaf(a.z, b.z, a.w * b.w)));
}

__device__ inline float sel4(float a0, float a1, float a2, float a3, int i) {
    float r = a0;
    r = (i == 1) ? a1 : r;
    r = (i == 2) ? a2 : r;
    r = (i == 3) ? a3 : r;
    return r;
}

__device__ inline short f2h_bits(float v) {
    _Float16 h = (_Float16)v;
    return *(short*)&h;
}

__device__ inline void f16split2(float v, _Float16& h, _Float16& l) {
    h = (_Float16)v;
    l = (_Float16)(v - (float)h);
}

// ---------------- unified pack kernel: conv filters + emb_w + layer weights ----------------
__global__ __launch_bounds__(512)
void pack_all_kernel(const float* __restrict__ filt, const float* __restrict__ emb_w,
                     const float* __restrict__ wo, const float* __restrict__ wq,
                     const float* __restrict__ wk, const float* __restrict__ wv,
                     const float* __restrict__ c1w, const float* __restrict__ c2w,
                     short* __restrict__ fpH, short* __restrict__ wpH,
                     short* __restrict__ lw) {
    int bx = blockIdx.x;
    int t = threadIdx.x, lane = t >> 3, e = t & 7;
    if (bx < 520) {
        // conv filter pack: fragment-major [ft][kc][lane][8]
        int ft = bx / 65, kc = bx % 65;
        int f = ft * 32 + (lane & 31);
        int tap = kc * 16 + (lane >> 5) * 8 + e;
        float v = (tap < KF) ? filt[f * KF + tap] : 0.f;
        fpH[bx * 512 + t] = f2h_bits(v);
    } else if (bx < 520 + 8 * NKC) {
        // emb_w pack: fragment-major [ft][kc][lane][8]
        int blk = bx - 520;
        int ft = blk / NKC, kc = blk % NKC;
        int row = ft * 32 + (lane & 31);
        int tap = kc * 16 + (lane >> 5) * 8 + e;
        float v = (tap < KEMB) ? emb_w[(long)row * KEMB + tap] : 0.f;
        wpH[(long)blk * 512 + t] = f2h_bits(v);
    } else {
        // layer weight pack for 16x16x32 B-operand
        int b = bx - 520 - 8 * NKC;
        int layer = b / 1536, r = b % 1536;
        const float* src;
        int K, t2;
        long dst;
        if (r < 512) {
            int mat = r >> 7; t2 = r & 127;
            const float* m0 = (mat == 0 ? wo : mat == 1 ? wq : mat == 2 ? wk : wv);
            src = m0 + (long)layer * 65536; K = 256;
            dst = (long)layer * LWSZ + (long)mat * 65536 + (long)t2 * 512;
        } else if (r < 1024) {
            t2 = r - 512;
            src = c1w + (long)layer * 262144; K = 256;
            dst = (long)layer * LWSZ + 262144 + (long)t2 * 512;
        } else {
            t2 = r - 1024;
            src = c2w + (long)layer * 262144; K = 1024;
            dst = (long)layer * LWSZ + 524288 + (long)t2 * 512;
        }
        int KB = K >> 5;
        int nt = t2 / KB, kb = t2 % KB;
        int n = nt * 16 + (lane & 15);
        int k = kb * 32 + ((lane >> 4) & 3) * 8 + e;
        lw[dst + t] = f2h_bits(src[(long)n * K + k]);
    }
}

// ---------------- MFMA projection helper: one 16-col tile, M=16-padded (4 real rows) ----------
__device__ inline f32x4 mfma_nt(const _Float16* __restrict__ Xh, const _Float16* __restrict__ Xl,
                                int xstride, const short* __restrict__ wp_nt, int KB, int lane) {
    f32x4 acc = {0.f, 0.f, 0.f, 0.f};
    const int row = (lane & 15) & 3;
    const int ko0 = ((lane >> 4) & 3) * 8;
    const short* bp = wp_nt + lane * 8;
    const _Float16* xh = Xh + row * xstride + ko0;
    const _Float16* xl = Xl + row * xstride + ko0;
#pragma unroll 4
    for (int kb = 0; kb < KB; kb++) {
        f16x8 bf = *(const f16x8*)(bp + kb * 512);
        f16x8 ah = *(const f16x8*)(xh + kb * 32);
        f16x8 al = *(const f16x8*)(xl + kb * 32);
        acc = __builtin_amdgcn_mfma_f32_16x16x32_f16(al, bf, acc, 0, 0, 0);
        acc = __builtin_amdgcn_mfma_f32_16x16x32_f16(ah, bf, acc, 0, 0, 0);
    }
    return acc;
}

// ---------------- SincConv via MFMA (fp16 single-pass) + |.| + maxpool3 ----------------
union ConvLDS {
    short xh[8][RS];
    float ebuf[96][129];
};

__global__ __launch_bounds__(256, 3)
void conv_mfma_kernel(const float* __restrict__ x, const short* __restrict__ fpH,
                      _Float16* __restrict__ h) {
    __shared__ ConvLDS u;
    const int tid = threadIdx.x;
    const int pb = blockIdx.x;
    const int b = blockIdx.y;
    const int t0 = pb * 96;
    const float* xb = x + (long)b * L_IN;

    if (pb < 671) {
        for (int idx = tid; idx < 8 * NCH; idx += 256) {
            int s = idx / NCH, j = idx - s * NCH;
            int gi = t0 + s + j * 8;
            f16x8 hv;
#pragma unroll
            for (int e = 0; e < 8; e++) hv[e] = (_Float16)xb[gi + e];
            *(f16x8*)&u.xh[s][j * 8] = hv;
        }
    } else {
        for (int idx = tid; idx < 8 * NCH; idx += 256) {
            int s = idx / NCH, j = idx - s * NCH;
            int gi = t0 + s + j * 8;
            f16x8 hv;
#pragma unroll
            for (int e = 0; e < 8; e++) {
                float v = (gi + e < L_IN) ? xb[gi + e] : 0.f;
                hv[e] = (_Float16)v;
            }
            *(f16x8*)&u.xh[s][j * 8] = hv;
        }
    }
    __syncthreads();

    const int lane = tid & 63;
    const int wid = tid >> 6;
    const int l31 = lane & 31;
    const int hi = lane >> 5;
    const int f0w = wid * 64;

    const short* aH = &u.xh[l31 & 7][8 * (l31 >> 3) + 8 * hi];
    const short* bp0 = fpH + (long)(wid * 2) * FTILE + lane * 8;
    const short* bp1 = bp0 + FTILE;

    f32x16 a00 = {0}, a01 = {0}, a10 = {0}, a11 = {0}, a20 = {0}, a21 = {0};

#pragma unroll 1
    for (int kc = 0; kc < 65; kc++) {
        const int ko = kc * 16;
        const int kf = kc * 512;
        f16x8 ah0 = *(const f16x8*)(aH + ko);
        f16x8 ah1 = *(const f16x8*)(aH + ko + 32);
        f16x8 ah2 = *(const f16x8*)(aH + ko + 64);
        f16x8 bh0 = *(const f16x8*)(bp0 + kf);
        f16x8 bh1 = *(const f16x8*)(bp1 + kf);
        a00 = __builtin_amdgcn_mfma_f32_32x32x16_f16(ah0, bh0, a00, 0, 0, 0);
        a01 = __builtin_amdgcn_mfma_f32_32x32x16_f16(ah0, bh1, a01, 0, 0, 0);
        a10 = __builtin_amdgcn_mfma_f32_32x32x16_f16(ah1, bh0, a10, 0, 0, 0);
        a11 = __builtin_amdgcn_mfma_f32_32x32x16_f16(ah1, bh1, a11, 0, 0, 0);
        a20 = __builtin_amdgcn_mfma_f32_32x32x16_f16(ah2, bh0, a20, 0, 0, 0);
        a21 = __builtin_amdgcn_mfma_f32_32x32x16_f16(ah2, bh1, a21, 0, 0, 0);
    }

    __syncthreads();
    const int t3l = tid & 31;
    const int t3 = pb * 32 + t3l;

#pragma unroll
    for (int half = 0; half < 2; half++) {
        if ((wid >> 1) == half) {
            int fcb = f0w - half * 128;
#define WRF(ACC, MT, NT)                                                   \
            {                                                              \
                int fc = fcb + NT * 32 + l31;                              \
                _Pragma("unroll")                                          \
                for (int r = 0; r < 16; r++) {                             \
                    int pos = MT * 32 + (r & 3) + 8 * (r >> 2) + 4 * hi;   \
                    u.ebuf[pos][fc] = fabsf(ACC[r]);                       \
                }                                                          \
            }
            WRF(a00, 0, 0) WRF(a01, 0, 1)
            WRF(a10, 1, 0) WRF(a11, 1, 1)
            WRF(a20, 2, 0) WRF(a21, 2, 1)
#undef WRF
        }
        __syncthreads();
        if (t3 < T_POOL) {
            for (int ff = tid >> 5; ff < 128; ff += 8) {
                float v = fmaxf(fmaxf(u.ebuf[3 * t3l][ff], u.ebuf[3 * t3l + 1][ff]),
                                u.ebuf[3 * t3l + 2][ff]);
                h[((long)(b * 256 + half * 128 + ff)) * TPP + t3] = (_Float16)v;
            }
        }
        __syncthreads();
    }
}

// ---------------- BatchNorm stats for h (fp16): two-stage ----------------
__global__ __launch_bounds__(256)
void bn_part_kernel(const _Float16* __restrict__ xin, float* __restrict__ p1,
                    float* __restrict__ p2) {
    __shared__ float sm[8];
    int c = blockIdx.x, s = blockIdx.y, tid = threadIdx.x;
    int t0 = s * 2687, t1 = min(T_POOL, t0 + 2687);
    float s1 = 0.f, s2 = 0.f;
    for (int b = 0; b < 4; b++) {
        const _Float16* p = xin + (long)b * 256 * TPP + (long)c * TPP;
        for (int t = t0 + tid; t < t1; t += 256) {
            float v = (float)p[t];
            s1 += v;
            s2 = fmaf(v, v, s2);
        }
    }
    for (int off = 32; off > 0; off >>= 1) { s1 += __shfl_down(s1, off); s2 += __shfl_down(s2, off); }
    int lane = tid & 63, wv = tid >> 6;
    if (lane == 0) { sm[wv] = s1; sm[4 + wv] = s2; }
    __syncthreads();
    if (tid == 0) {
        p1[c * 8 + s] = sm[0] + sm[1] + sm[2] + sm[3];
        p2[c * 8 + s] = sm[4] + sm[5] + sm[6] + sm[7];
    }
}

__global__ __launch_bounds__(256)
void bn_fin_kernel(const float* __restrict__ p1, const float* __restrict__ p2,
                   const float* __restrict__ g, const float* __restrict__ bb,
                   float* __restrict__ sc, float* __restrict__ sh) {
    int c = threadIdx.x;
    float S1 = 0.f, S2 = 0.f;
#pragma unroll
    for (int s = 0; s < 8; s++) { S1 += p1[c * 8 + s]; S2 += p2[c * 8 + s]; }
    float n = 4.f * (float)T_POOL;
    float mean = S1 / n;
    float var = S2 / n - mean * mean;
    float rstd = rsqrtf(var + 1e-5f);
    float gc = g[c], bc = bb[c];
    sc[c] = rstd * gc;
    sh[c] = bc - mean * rstd * gc;
}

// ---------------- Embedding GEMM via MFMA (fp16 single-pass), split-K, packed B ----------------
__global__ __launch_bounds__(256, 2)
void embed_mfma_kernel(const _Float16* __restrict__ H, const short* __restrict__ Wh,
                       const float* __restrict__ sc, const float* __restrict__ sh,
                       float* __restrict__ P, int kPerZ) {
    __shared__ short Ah[128][36];
    const int tid = threadIdx.x;
    const int rowBase = blockIdx.x * 128;
    const int colBase = blockIdx.y * 128;
    const int z = blockIdx.z;
    const int kz = z * kPerZ;
    const int iters = kPerZ >> 5;

    const int trow = tid >> 1, th = (tid & 1) * 16;
    const int arow = rowBase + trow;
    const float asc = sc[arow & 255], ash_ = sh[arow & 255];
    const _Float16* Ap = H + (long)arow * TPP;

    const int lane = tid & 63, wid = tid >> 6;
    const int l31 = lane & 31, hi = lane >> 5;
    const int wm = wid >> 1, wn = wid & 1;

    const short* bhp[2];
#pragma unroll
    for (int nt = 0; nt < 2; nt++) {
        int ft = (colBase >> 5) + wn * 2 + nt;
        bhp[nt] = Wh + (long)ft * NKC * 512 + lane * 8;
    }

    f32x16 acc[2][2] = {{{0}, {0}}, {{0}, {0}}};

    for (int it = 0; it < iters; it++) {
        const int k0 = kz + it * 32;
        __syncthreads();
        float av[16];
        if (k0 + 32 <= KEMB) {
            const f16x8* p8 = (const f16x8*)(Ap + k0 + th);
            f16x8 v0 = p8[0], v1 = p8[1];
#pragma unroll
            for (int e = 0; e < 8; e++) { av[e] = (float)v0[e]; av[8 + e] = (float)v1[e]; }
        } else {
#pragma unroll
            for (int e = 0; e < 16; e++) {
                int k = k0 + th + e;
                av[e] = (k < KEMB) ? (float)Ap[k] : 0.f;
            }
        }
#pragma unroll
        for (int q = 0; q < 4; q++) {
            s16x4 h4;
#pragma unroll
            for (int e = 0; e < 4; e++) {
                float v = selu_f(fmaf(av[q * 4 + e], asc, ash_));
                h4[e] = f2h_bits(v);
            }
            *(s16x4*)&Ah[trow][th + q * 4] = h4;
        }
        __syncthreads();

#pragma unroll
        for (int ks = 0; ks < 2; ks++) {
            const int kloc = ks * 16 + hi * 8;
            const long kcg = (long)((k0 >> 4) + ks) * 512;
            f16x8 ah[2], bh[2];
#pragma unroll
            for (int mt = 0; mt < 2; mt++) {
                const int r = wm * 64 + mt * 32 + l31;
                const short* ph = &Ah[r][kloc];
                union { f16x8 v; unsigned long long q[2]; } uh;
                uh.q[0] = *(const unsigned long long*)(ph);
                uh.q[1] = *(const unsigned long long*)(ph + 4);
                ah[mt] = uh.v;
            }
#pragma unroll
            for (int nt = 0; nt < 2; nt++)
                bh[nt] = *(const f16x8*)(bhp[nt] + kcg);
#pragma unroll
            for (int mt = 0; mt < 2; mt++)
#pragma unroll
                for (int nt = 0; nt < 2; nt++)
                    acc[mt][nt] = __builtin_amdgcn_mfma_f32_32x32x16_f16(ah[mt], bh[nt], acc[mt][nt], 0, 0, 0);
        }
    }

    float* Pz = P + (long)z * 262144;
#pragma unroll
    for (int mt = 0; mt < 2; mt++)
#pragma unroll
        for (int nt = 0; nt < 2; nt++) {
            int col = colBase + wn * 64 + nt * 32 + l31;
#pragma unroll
            for (int r = 0; r < 16; r++) {
                int row = rowBase + wm * 64 + mt * 32 + (r & 3) + 8 * (r >> 2) + 4 * hi;
                Pz[(long)row * 256 + col] = acc[mt][nt][r];
            }
        }
}

// ---------------- combine split-K partials + e-BN per-row partial stats ----------------
__global__ __launch_bounds__(256)
void embed_combine_kernel(const float* __restrict__ P, const float* __restrict__ eb,
                          float* __restrict__ e, float* __restrict__ ebnp, int nsplit) {
    __shared__ float sm[8];
    const int bid = blockIdx.x, tid = threadIdx.x;
    const int idx = bid * 256 + tid;
    float s = 0.f;
    for (int z = 0; z < nsplit; z++) s += P[(long)z * 262144 + idx];
    float v = s + eb[tid];
    e[idx] = v;
    float s1 = v, s2 = v * v;
    for (int off = 32; off > 0; off >>= 1) { s1 += __shfl_down(s1, off); s2 += __shfl_down(s2, off); }
    int lane = tid & 63, wv = tid >> 6;
    if (lane == 0) { sm[wv] = s1; sm[4 + wv] = s2; }
    __syncthreads();
    if (tid == 0) {
        ebnp[bid * 2] = sm[0] + sm[1] + sm[2] + sm[3];
        ebnp[bid * 2 + 1] = sm[4] + sm[5] + sm[6] + sm[7];
    }
}

// ---------------- fused e-BN finalize + zinit + layer-0 QKV (MFMA) ----------------
__global__ __launch_bounds__(512)
void qkv_init_kernel(const float* __restrict__ e, const float* __restrict__ ebnp,
                     const float* __restrict__ bng, const float* __restrict__ bnb,
                     const short* __restrict__ lw0,
                     const float* __restrict__ bq0, const float* __restrict__ bk0,
                     const float* __restrict__ bv0,
                     float* __restrict__ z, float* __restrict__ qo,
                     float* __restrict__ ko, float* __restrict__ vo) {
    __shared__ _Float16 zsh[4][256], zsl[4][256];
    __shared__ float scs[4], shs[4];
    const int t = threadIdx.x;
    const int w = t >> 6, lane = t & 63;
    const long rowg0 = (long)blockIdx.x * 4;

    if (t < 4) {
        int c = (int)((rowg0 + t) & 255);
        float S1 = 0.f, S2 = 0.f;
#pragma unroll
        for (int b2 = 0; b2 < 4; b2++) {
            S1 += ebnp[(b2 * 256 + c) * 2];
            S2 += ebnp[(b2 * 256 + c) * 2 + 1];
        }
        float mean = S1 * (1.f / 1024.f);
        float var = S2 * (1.f / 1024.f) - mean * mean;
        float rstd = rsqrtf(var + 1e-5f);
        float gc = bng[c];
        scs[t] = rstd * gc;
        shs[t] = bnb[c] - mean * rstd * gc;
    }
    __syncthreads();

    for (int idx = t; idx < 1024; idx += 512) {
        int i = idx >> 8, dd = idx & 255;
        int c = (int)((rowg0 + i) & 255);
        float v = fmaf(e[(rowg0 + i) * 256 + dd], scs[i], shs[i]);
        v = fmaxf(v, 0.f);
        int i2 = dd >> 1;
        float ang = (float)c * expf(-0.03597789207803195f * (float)(2 * i2));
        float pe = (dd & 1) ? cosf(ang) : sinf(ang);
        float zz = v + pe;
        z[(rowg0 + i) * 256 + dd] = zz;
        _Float16 hh, ll;
        f16split2(zz, hh, ll);
        zsh[i][dd] = hh; zsl[i][dd] = ll;
    }
    __syncthreads();

#pragma unroll
    for (int mat = 0; mat < 3; mat++) {
        const short* wp = lw0 + 65536 * (1 + mat);
        const float* bb = (mat == 0 ? bq0 : mat == 1 ? bk0 : bv0);
        float* op = (mat == 0 ? qo : mat == 1 ? ko : vo);
        for (int nt = w; nt < 16; nt += 8) {
            f32x4 acc = mfma_nt(&zsh[0][0], &zsl[0][0], 256, wp + nt * 8 * 512, 8, lane);
            if (lane < 16) {
                int col = nt * 16 + lane;
                float bv2 = bb[col];
#pragma unroll
                for (int r = 0; r < 4; r++)
                    op[(rowg0 + r) * 256 + col] = acc[r] + bv2;
            }
        }
    }
}

// ---------------- fused transformer layer: attention GEMV + MFMA projections ----------------
__device__ inline void ln_reduce4(const float (*buf)[256], float (*mr)[2], int t) {
    int wid = t >> 6, lane = t & 63;
    if (wid < 4) {
        float4 v = *(const float4*)&buf[wid][lane * 4];
        float s = v.x + v.y + v.z + v.w;
        float q = v.x * v.x + v.y * v.y + v.z * v.z + v.w * v.w;
#pragma unroll
        for (int off = 32; off > 0; off >>= 1) {
            s += __shfl_xor(s, off);
            q += __shfl_xor(q, off);
        }
        if (lane == 0) {
            float mean = s * (1.f / 256.f);
            float var = q * (1.f / 256.f) - mean * mean;
            mr[wid][0] = mean;
            mr[wid][1] = rsqrtf(var + 1e-5f);
        }
    }
}

template <int LAST>
__global__ __launch_bounds__(1024)
void layer_kernel(const float* __restrict__ zin, const float* __restrict__ qin,
                  const float* __restrict__ kin, const float* __restrict__ vin,
                  const short* __restrict__ lw_l, const short* __restrict__ lw_n,
                  const float* __restrict__ bo_l,
                  const float* __restrict__ c1b_l, const float* __restrict__ c2b_l,
                  const float* __restrict__ ln1g_l, const float* __restrict__ ln1b_l,
                  const float* __restrict__ ln2g_l, const float* __restrict__ ln2b_l,
                  const float* __restrict__ bq_n, const float* __restrict__ bk_n,
                  const float* __restrict__ bv_n,
                  const float* __restrict__ lnfg, const float* __restrict__ lnfb,
                  float* __restrict__ zout, float* __restrict__ qo,
                  float* __restrict__ ko, float* __restrict__ vo,
                  float* __restrict__ lnf_out) {
    __shared__ float zs[4][256];
    __shared__ float qb[4][256];
    __shared__ float sscore[4][8][256];
    __shared__ _Float16 zsh[4][256], zsl[4][256];
    __shared__ _Float16 yh[4][1024], yl[4][1024];
    __shared__ float mr[4][2];

    const int t = threadIdx.x;
    const int w = t >> 6, lane = t & 63;
    const long rowg0 = (long)blockIdx.x * 4;
    const int b = blockIdx.x >> 6;

    const int f = t & 255;
    const int kq = t >> 8;

    {
        int r = t >> 8, dd = t & 255;
        zs[r][dd] = zin[(rowg0 + r) * 256 + dd];
        qb[r][dd] = qin[(rowg0 + r) * 256 + dd];
    }
    __syncthreads();

    {
        const float scale = 0.17677669529663687f;
        const int jq = lane >> 3, li = lane & 7, d4 = li * 4;
        const int hh = w >> 1, jh = w & 1;
        const float* kb = kin + (long)b * 65536 + hh * 32 + d4;
        float4 q0 = *(const float4*)&qb[0][hh * 32 + d4];
        float4 q1 = *(const float4*)&qb[1][hh * 32 + d4];
        float4 q2 = *(const float4*)&qb[2][hh * 32 + d4];
        float4 q3 = *(const float4*)&qb[3][hh * 32 + d4];
        for (int jb = 0; jb < 16; jb++) {
            int j = jh * 128 + jb * 8 + jq;
            float4 kv = *(const float4*)(kb + (long)j * 256);
            float a0 = dot4(kv, q0), a1 = dot4(kv, q1);
            float a2 = dot4(kv, q2), a3 = dot4(kv, q3);
#pragma unroll
            for (int off = 1; off < 8; off <<= 1) {
                a0 += __shfl_xor(a0, off); a1 += __shfl_xor(a1, off);
                a2 += __shfl_xor(a2, off); a3 += __shfl_xor(a3, off);
            }
            if (li < 4) sscore[li][hh][j] = sel4(a0, a1, a2, a3, li) * scale;
        }
    }
    __syncthreads();

    {
#pragma unroll
        for (int p = 0; p < 2; p++) {
            int pair = w * 2 + p;
            int i = pair >> 3, hh = pair & 7;
            float* row = sscore[i][hh];
            float v0 = row[lane], v1 = row[lane + 64];
            float v2 = row[lane + 128], v3 = row[lane + 192];
            float m = fmaxf(fmaxf(v0, v1), fmaxf(v2, v3));
#pragma unroll
            for (int off = 32; off > 0; off >>= 1) m = fmaxf(m, __shfl_xor(m, off));
            float e0 = expf(v0 - m), e1 = expf(v1 - m);
            float e2 = expf(v2 - m), e3 = expf(v3 - m);
            float su = e0 + e1 + e2 + e3;
#pragma unroll
            for (int off = 32; off > 0; off >>= 1) su += __shfl_xor(su, off);
            float inv = 1.f / su;
            row[lane] = e0 * inv; row[lane + 64] = e1 * inv;
            row[lane + 128] = e2 * inv; row[lane + 192] = e3 * inv;
        }
    }
    __syncthreads();

    {
        int row = kq;
        int hh = f >> 5;
        const float* vcol = vin + (long)b * 65536 + f;
        const float* p0 = sscore[row][hh];
        float a0 = 0.f;
#pragma unroll 4
        for (int j4 = 0; j4 < 64; j4++) {
            float4 pv0 = *(const float4*)(p0 + j4 * 4);
            float v0 = vcol[(long)(j4 * 4 + 0) * 256];
            float v1 = vcol[(long)(j4 * 4 + 1) * 256];
            float v2 = vcol[(long)(j4 * 4 + 2) * 256];
            float v3 = vcol[(long)(j4 * 4 + 3) * 256];
            a0 = fmaf(pv0.x, v0, a0); a0 = fmaf(pv0.y, v1, a0);
            a0 = fmaf(pv0.z, v2, a0); a0 = fmaf(pv0.w, v3, a0);
        }
        _Float16 hh2, ll;
        f16split2(a0, hh2, ll);
        zsh[row][f] = hh2; zsl[row][f] = ll;
    }
    __syncthreads();

    {
        int nt = w;
        f32x4 acc = mfma_nt(&zsh[0][0], &zsl[0][0], 256, lw_l + nt * 8 * 512, 8, lane);
        if (lane < 16) {
            int col = nt * 16 + lane;
            float bb = bo_l[col];
#pragma unroll
            for (int r = 0; r < 4; r++)
                qb[r][col] = acc[r] + bb + zs[r][col];
        }
    }
    __syncthreads();
    ln_reduce4(qb, mr, t);
    __syncthreads();
    {
        int r = kq;
        float z1 = (qb[r][f] - mr[r][0]) * mr[r][1] * ln1g_l[f] + ln1b_l[f];
        zs[r][f] = z1;
        _Float16 hh2, ll;
        f16split2(z1, hh2, ll);
        zsh[r][f] = hh2; zsl[r][f] = ll;
    }
    __syncthreads();

    {
        const short* wp = lw_l + 262144;
        for (int nt = w; nt < 64; nt += 16) {
            f32x4 acc = mfma_nt(&zsh[0][0], &zsl[0][0], 256, wp + nt * 8 * 512, 8, lane);
            if (lane < 16) {
                int col = nt * 16 + lane;
                float cb = c1b_l[col];
#pragma unroll
                for (int r = 0; r < 4; r++) {
                    float g = gelu_f(acc[r] + cb);
                    _Float16 hh2, ll;
                    f16split2(g, hh2, ll);
                    yh[r][col] = hh2; yl[r][col] = ll;
                }
            }
        }
    }
    __syncthreads();

    {
        const short* wp = lw_l + 524288;
        int nt = w;
        f32x4 acc = mfma_nt(&yh[0][0], &yl[0][0], 1024, wp + nt * 32 * 512, 32, lane);
        if (lane < 16) {
            int col = nt * 16 + lane;
            float cb = c2b_l[col];
#pragma unroll
            for (int r = 0; r < 4; r++)
                qb[r][col] = acc[r] + cb + zs[r][col];
        }
    }
    __syncthreads();
    ln_reduce4(qb, mr, t);
    __syncthreads();
    {
        int r = kq;
        float z2 = (qb[r][f] - mr[r][0]) * mr[r][1] * ln2g_l[f] + ln2b_l[f];
        zs[r][f] = z2;
        zout[(rowg0 + r) * 256 + f] = z2;
        _Float16 hh2, ll;
        f16split2(z2, hh2, ll);
        zsh[r][f] = hh2; zsl[r][f] = ll;
    }
    __syncthreads();

    if (!LAST) {
#pragma unroll
        for (int mat = 0; mat < 3; mat++) {
            const short* wp = lw_n + 65536 * (1 + mat);
            const float* bb = (mat == 0 ? bq_n : mat == 1 ? bk_n : bv_n);
            float* op = (mat == 0 ? qo : mat == 1 ? ko : vo);
            int nt = w;
            f32x4 acc = mfma_nt(&zsh[0][0], &zsl[0][0], 256, wp + nt * 8 * 512, 8, lane);
            if (lane < 16) {
                int col = nt * 16 + lane;
                float bv2 = bb[col];
#pragma unroll
                for (int r = 0; r < 4; r++)
                    op[(rowg0 + r) * 256 + col] = acc[r] + bv2;
            }
        }
    } else {
        ln_reduce4(zs, mr, t);
        __syncthreads();
        {
            int r = kq;
            lnf_out[(rowg0 + r) * 256 + f] =
                (zs[r][f] - mr[r][0]) * mr[r][1] * lnfg[f] + lnfb[f];
        }
    }
}

// ---------------- final: pooled mean over seq -> proj ----------------
__global__ __launch_bounds__(256)
void final_kernel(const float* __restrict__ zf, const float* __restrict__ pw,
                  const float* __restrict__ pb, float* __restrict__ out) {
    __shared__ float sm[8];
    int b = blockIdx.x, d = threadIdx.x;
    float s = 0.f;
    for (int c = 0; c < 256; c++) s += zf[((long)(b * 256 + c)) * 256 + d];
    float pooled = s * (1.f / 256.f);
    float c0 = pooled * pw[d], c1 = pooled * pw[256 + d];
    for (int off = 32; off > 0; off >>= 1) { c0 += __shfl_down(c0, off); c1 += __shfl_down(c1, off); }
    int lane = d & 63, wv = d >> 6;
    if (lane == 0) { sm[wv] = c0; sm[4 + wv] = c1; }
    __syncthreads();
    if (d == 0) {
        out[b * 2 + 0] = sm[0] + sm[1] + sm[2] + sm[3] + pb[0];
        out[b * 2 + 1] = sm[4] + sm[5] + sm[6] + sm[7] + pb[1];
    }
}

extern "C" void kernel_launch(void* const* d_in, const int* in_sizes, int n_in,
                              void* d_out, int out_size, void* d_ws, size_t ws_size,
                              hipStream_t stream) {
    const float* x       = (const float*)d_in[0];
    const float* filters = (const float*)d_in[1];
    const float* bn1_g   = (const float*)d_in[2];
    const float* bn1_b   = (const float*)d_in[3];
    const float* emb_w   = (const float*)d_in[4];
    const float* emb_b   = (const float*)d_in[5];
    const float* embbn_g = (const float*)d_in[6];
    const float* embbn_b = (const float*)d_in[7];
    const float* wq      = (const float*)d_in[8];
    const float* bq      = (const float*)d_in[9];
    const float* wk      = (const float*)d_in[10];
    const float* bk      = (const float*)d_in[11];
    const float* wv      = (const float*)d_in[12];
    const float* bv      = (const float*)d_in[13];
    const float* wo      = (const float*)d_in[14];
    const float* bo      = (const float*)d_in[15];
    const float* c1w     = (const float*)d_in[16];
    const float* c1b     = (const float*)d_in[17];
    const float* c2w     = (const float*)d_in[18];
    const float* c2b     = (const float*)d_in[19];
    const float* ln1g    = (const float*)d_in[20];
    const float* ln1b    = (const float*)d_in[21];
    const float* ln2g    = (const float*)d_in[22];
    const float* ln2b    = (const float*)d_in[23];
    const float* lnfg    = (const float*)d_in[24];
    const float* lnfb    = (const float*)d_in[25];
    const float* projw   = (const float*)d_in[26];
    const float* projb   = (const float*)d_in[27];

    const long hF = 11005952L;                      // 1024*TPP halfs, in float units
    const long wpackF = 2752512L;                   // 8*NKC*512 shorts, in floats
    const long lwF = 1572864L;                      // 4*LWSZ shorts, in floats
    const long fixedF = hF + 6656 + wpackF + lwF + 9L * 262144;
    long wsFloats = (long)(ws_size / 4);
    long Z = 32;
    while (Z > 8 && fixedF + Z * 262144L > wsFloats) Z >>= 1;
    const int kPerZ = KEMBP / (int)Z;

    float* ws = (float*)d_ws;
    _Float16* h16 = (_Float16*)ws;                  // 1024*TPP halfs
    float* bn1_sc = ws + hF;
    float* bn1_sh = bn1_sc + 256;
    float* ebnp   = bn1_sh + 256;                   // 2048
    float* bnp1   = ebnp + 2048;                    // 2048
    float* bnp2   = bnp1 + 2048;                    // 2048
    float* part   = bnp2 + 2048;                    // Z * 262144
    float* wsp    = part + Z * 262144L;
    short* wpH    = (short*)wsp;                    // 8*NKC*512 shorts
    float* e      = wsp + wpackF;
    float* z      = e + 262144;
    float* qA     = z + 262144;
    float* kA     = qA + 262144;
    float* vA     = kA + 262144;
    float* qB     = vA + 262144;
    float* kB     = qB + 262144;
    float* vB     = kB + 262144;
    float* t1     = vB + 262144;
    short* lw     = (short*)(t1 + 262144);          // 4*LWSZ shorts

    // conv packed filters alias onto `part` (only used before embed writes part)
    short* fpH = (short*)part;                      // 520*512 shorts

    pack_all_kernel<<<520 + 8 * NKC + 6144, 512, 0, stream>>>(
        filters, emb_w, wo, wq, wk, wv, c1w, c2w, fpH, wpH, lw);
    conv_mfma_kernel<<<dim3(672, 4), 256, 0, stream>>>(x, fpH, h16);
    bn_part_kernel<<<dim3(256, 8), 256, 0, stream>>>(h16, bnp1, bnp2);
    bn_fin_kernel<<<1, 256, 0, stream>>>(bnp1, bnp2, bn1_g, bn1_b, bn1_sc, bn1_sh);
    embed_mfma_kernel<<<dim3(8, 2, (int)Z), 256, 0, stream>>>(h16, wpH,
                                                              bn1_sc, bn1_sh, part, kPerZ);
    embed_combine_kernel<<<1024, 256, 0, stream>>>(part, emb_b, e, ebnp, (int)Z);
    qkv_init_kernel<<<256, 512, 0, stream>>>(e, ebnp, embbn_g, embbn_b, lw,
                                             bq, bk, bv, z, qA, kA, vA);

    float* qs[2][3] = {{qA, kA, vA}, {qB, kB, vB}};
    for (int l = 0; l < 4; l++) {
        float** in = qs[l & 1];
        float** ou = qs[(l + 1) & 1];
        const short* lw_l = lw + (long)l * LWSZ;
        const short* lw_n = lw + (long)((l + 1) & 3) * LWSZ;
        const float* bo_l = bo + l * 256;
        const float* c1b_l = c1b + l * 1024;
        const float* c2b_l = c2b + l * 256;
        const float* l1g = ln1g + l * 256; const float* l1b = ln1b + l * 256;
        const float* l2g = ln2g + l * 256; const float* l2b = ln2b + l * 256;
        if (l < 3) {
            const float* bq_n = bq + (l + 1) * 256;
            const float* bk_n = bk + (l + 1) * 256;
            const float* bv_n = bv + (l + 1) * 256;
            layer_kernel<0><<<256, 1024, 0, stream>>>(z, in[0], in[1], in[2],
                lw_l, lw_n, bo_l, c1b_l, c2b_l, l1g, l1b, l2g, l2b,
                bq_n, bk_n, bv_n, lnfg, lnfb,
                z, ou[0], ou[1], ou[2], t1);
        } else {
            layer_kernel<1><<<256, 1024, 0, stream>>>(z, in[0], in[1], in[2],
                lw_l, lw_n, bo_l, c1b_l, c2b_l, l1g, l1b, l2g, l2b,
                bq, bk, bv, lnfg, lnfb,
                z, ou[0], ou[1], ou[2], t1);
        }
    }

    final_kernel<<<4, 256, 0, stream>>>(t1, projw, projb, (float*)d_out);
}